// Round 1
// baseline (508.760 us; speedup 1.0000x reference)
//
#include <hip/hip_runtime.h>
#include <hip/hip_bf16.h>

#define B_ 256
#define S_ 512
#define F_ 256
#define L_ 20

// ws layout (floats): [0,10240) W_combT [512][20]; [10240,10260) b_comb; [16384, +B*F*20) x_t
#define WS_WCT 0
#define WS_BC  10240
#define WS_XT  16384

#define LOAD20(dst, ptr) { const float4* _p = (const float4*)(ptr); \
  float4 _a=_p[0], _b=_p[1], _c=_p[2], _d=_p[3], _e=_p[4]; \
  dst[0]=_a.x; dst[1]=_a.y; dst[2]=_a.z; dst[3]=_a.w; \
  dst[4]=_b.x; dst[5]=_b.y; dst[6]=_b.z; dst[7]=_b.w; \
  dst[8]=_c.x; dst[9]=_c.y; dst[10]=_c.z; dst[11]=_c.w; \
  dst[12]=_d.x; dst[13]=_d.y; dst[14]=_d.z; dst[15]=_d.w; \
  dst[16]=_e.x; dst[17]=_e.y; dst[18]=_e.z; dst[19]=_e.w; }

// ---------------- kernel 1: W_comb = W_up @ W_N (transposed store), b_comb ----------------
__global__ __launch_bounds__(256) void prep_kernel(
    const float* __restrict__ W_N, const float* __restrict__ b_N,
    const float* __restrict__ W_up, const float* __restrict__ b_up,
    float* __restrict__ wsF)
{
  int idx = blockIdx.x * 256 + threadIdx.x;
  if (idx < 10240) {
    int s = idx / 20, l = idx % 20;
    float acc = 0.f;
    for (int t = 0; t < S_; ++t)
      acc = fmaf(W_up[l * S_ + t], W_N[t * S_ + s], acc);
    wsF[WS_WCT + idx] = acc;          // W_combT[s][l]
  } else if (idx < 10260) {
    int j = idx - 10240;
    float acc = b_up[j];
    for (int t = 0; t < S_; ++t)
      acc = fmaf(W_up[j * S_ + t], b_N[t], acc);
    wsF[idx] = acc;                   // b_comb[j]
  }
}

// ---------------- kernel 2: x_t[b][f][l] = b_comb[l] + sum_s W_comb[l][s] * x[b][s][f] ----
__global__ __launch_bounds__(512) void xup_kernel(
    const float* __restrict__ x, const float* __restrict__ wsF,
    float* __restrict__ xt)
{
  __shared__ __align__(16) float Wl[10240];       // W_combT [512][20], 40KB
  __shared__ __align__(16) float part[F_ * L_];   // 20KB partials from p=1 half
  int b = blockIdx.x;
  int tid = threadIdx.x;
  {
    const float4* srcw = (const float4*)(wsF + WS_WCT);
    float4* dstw = (float4*)Wl;
    for (int i = tid; i < 10240 / 4; i += 512) dstw[i] = srcw[i];
  }
  __syncthreads();
  int f = tid & 255;
  int p = tid >> 8;                 // s-parity split across wave groups
  float acc[20];
#pragma unroll
  for (int l = 0; l < 20; ++l) acc[l] = 0.f;
  const float* xb = x + (size_t)b * S_ * F_ + f;
#pragma unroll 1
  for (int sg = 0; sg < S_; sg += 16) {
    float xv[8];
#pragma unroll
    for (int u = 0; u < 8; ++u) xv[u] = xb[(size_t)(sg + p + 2 * u) * F_];
#pragma unroll
    for (int u = 0; u < 8; ++u) {
      int s = sg + p + 2 * u;
      const float4* wp = (const float4*)(Wl + s * 20);
      float4 w0 = wp[0], w1 = wp[1], w2 = wp[2], w3 = wp[3], w4 = wp[4];
      acc[0] = fmaf(w0.x, xv[u], acc[0]);  acc[1] = fmaf(w0.y, xv[u], acc[1]);
      acc[2] = fmaf(w0.z, xv[u], acc[2]);  acc[3] = fmaf(w0.w, xv[u], acc[3]);
      acc[4] = fmaf(w1.x, xv[u], acc[4]);  acc[5] = fmaf(w1.y, xv[u], acc[5]);
      acc[6] = fmaf(w1.z, xv[u], acc[6]);  acc[7] = fmaf(w1.w, xv[u], acc[7]);
      acc[8] = fmaf(w2.x, xv[u], acc[8]);  acc[9] = fmaf(w2.y, xv[u], acc[9]);
      acc[10] = fmaf(w2.z, xv[u], acc[10]); acc[11] = fmaf(w2.w, xv[u], acc[11]);
      acc[12] = fmaf(w3.x, xv[u], acc[12]); acc[13] = fmaf(w3.y, xv[u], acc[13]);
      acc[14] = fmaf(w3.z, xv[u], acc[14]); acc[15] = fmaf(w3.w, xv[u], acc[15]);
      acc[16] = fmaf(w4.x, xv[u], acc[16]); acc[17] = fmaf(w4.y, xv[u], acc[17]);
      acc[18] = fmaf(w4.z, xv[u], acc[18]); acc[19] = fmaf(w4.w, xv[u], acc[19]);
    }
  }
  if (p == 1) {
#pragma unroll
    for (int l = 0; l < 20; ++l) part[f * 20 + l] = acc[l];
  }
  __syncthreads();
  if (p == 0) {
#pragma unroll
    for (int l = 0; l < 20; ++l) acc[l] += part[f * 20 + l] + wsF[WS_BC + l];
    float4* o = (float4*)(xt + ((size_t)b * F_ + f) * 20);
    o[0] = make_float4(acc[0], acc[1], acc[2], acc[3]);
    o[1] = make_float4(acc[4], acc[5], acc[6], acc[7]);
    o[2] = make_float4(acc[8], acc[9], acc[10], acc[11]);
    o[3] = make_float4(acc[12], acc[13], acc[14], acc[15]);
    o[4] = make_float4(acc[16], acc[17], acc[18], acc[19]);
  }
}

// ---------------- kernel 3: bidirectional 2-layer LSTM chain + final projection ----------
__device__ __forceinline__ float sigm(float x) {
  return __builtin_amdgcn_rcpf(1.f + __expf(-x));
}
__device__ __forceinline__ float tanh_fast(float x) {
  return fmaf(2.f, __builtin_amdgcn_rcpf(1.f + __expf(-2.f * x)), -1.f);
}

__global__ __launch_bounds__(128) void lstm_kernel(
    const float* __restrict__ xt, const float* __restrict__ mu,
    const float* __restrict__ Wih0, const float* __restrict__ Whh0,
    const float* __restrict__ bih0, const float* __restrict__ bhh0,
    const float* __restrict__ Wih1, const float* __restrict__ Whh1,
    const float* __restrict__ bih1, const float* __restrict__ bhh1,
    const float* __restrict__ Wv, const float* __restrict__ bv,
    float* __restrict__ out)
{
  __shared__ __align__(16) float tile[F_ * L_];   // x_t[b] : [256][20]
  __shared__ __align__(16) float hb[2][2][20];    // [wave][layer][unit] broadcast
  int b = blockIdx.x;
  int tid = threadIdx.x;
  int wave = tid >> 6;      // 0 = fwd sample b, 1 = rev sample B+b
  int lane = tid & 63;
  {
    const float4* src = (const float4*)(xt + (size_t)b * F_ * L_);
    float4* dst = (float4*)tile;
#pragma unroll 1
    for (int i = tid; i < (F_ * L_) / 4; i += 128) dst[i] = src[i];
  }
  __syncthreads();

  int g1 = lane;                 // round-1 gate
  int gi = lane & 15, p2 = lane >> 4;
  int g2 = 64 + gi;              // round-2 gate (o_4..o_19), K-split 4 ways by p2
  float wiA0[20], whA0[20], wiA1[20], whA1[20];
#pragma unroll
  for (int k = 0; k < 20; ++k) {
    wiA0[k] = Wih0[g1 * 20 + k]; whA0[k] = Whh0[g1 * 20 + k];
    wiA1[k] = Wih1[g1 * 20 + k]; whA1[k] = Whh1[g1 * 20 + k];
  }
  float wiB0[5], whB0[5], wiB1[5], whB1[5];
#pragma unroll
  for (int k = 0; k < 5; ++k) {
    wiB0[k] = Wih0[g2 * 20 + p2 * 5 + k]; whB0[k] = Whh0[g2 * 20 + p2 * 5 + k];
    wiB1[k] = Wih1[g2 * 20 + p2 * 5 + k]; whB1[k] = Whh1[g2 * 20 + p2 * 5 + k];
  }
  float bA0 = bih0[g1] + bhh0[g1];
  float bA1 = bih1[g1] + bhh1[g1];
  float bB0 = bih0[g2] + bhh0[g2];
  float bB1 = bih1[g2] + bhh1[g2];
  int typ = g1 / 20;                       // 0:i 1:f 2:g 3:o
  float actB = (typ == 2) ? -2.f : -1.f;
  float actA = (typ == 2) ? 2.f : 1.f;
  float actC = (typ == 2) ? -1.f : 0.f;

  float h1a[20], h2a[20], xc[20];
#pragma unroll
  for (int k = 0; k < 20; ++k) { h1a[k] = 0.f; h2a[k] = 0.f; xc[k] = mu[k]; }
  float c1 = 0.f, c2 = 0.f;

#pragma unroll 1
  for (int t = 0; t < 257; ++t) {
    // ---- L2 hh dot with OLD h2a (independent -> hides h2 broadcast latency) ----
    float hh2q0 = 0.f, hh2q1 = 0.f, hh2q2 = 0.f, hh2q3 = 0.f;
#pragma unroll
    for (int k = 0; k < 5; ++k) {
      hh2q0 = fmaf(whA1[4 * k + 0], h2a[4 * k + 0], hh2q0);
      hh2q1 = fmaf(whA1[4 * k + 1], h2a[4 * k + 1], hh2q1);
      hh2q2 = fmaf(whA1[4 * k + 2], h2a[4 * k + 2], hh2q2);
      hh2q3 = fmaf(whA1[4 * k + 3], h2a[4 * k + 3], hh2q3);
    }
    float hh2 = (hh2q0 + hh2q1) + (hh2q2 + hh2q3);
    float hh2B = 0.f;
#pragma unroll
    for (int k = 0; k < 5; ++k) hh2B = fmaf(whB1[k], h2a[p2 * 5 + k], hh2B);

    // ---- L1 gates ----
    float s0 = bA0, s1 = 0.f, s2 = 0.f, s3 = 0.f;
#pragma unroll
    for (int k = 0; k < 5; ++k) {
      s0 = fmaf(wiA0[4 * k + 0], xc[4 * k + 0], s0);
      s1 = fmaf(wiA0[4 * k + 1], xc[4 * k + 1], s1);
      s2 = fmaf(wiA0[4 * k + 2], xc[4 * k + 2], s2);
      s3 = fmaf(wiA0[4 * k + 3], xc[4 * k + 3], s3);
    }
#pragma unroll
    for (int k = 0; k < 5; ++k) {
      s0 = fmaf(whA0[4 * k + 0], h1a[4 * k + 0], s0);
      s1 = fmaf(whA0[4 * k + 1], h1a[4 * k + 1], s1);
      s2 = fmaf(whA0[4 * k + 2], h1a[4 * k + 2], s2);
      s3 = fmaf(whA0[4 * k + 3], h1a[4 * k + 3], s3);
    }
    float pre1 = (s0 + s1) + (s2 + s3);
    float pre1B = 0.f;
#pragma unroll
    for (int k = 0; k < 5; ++k) pre1B = fmaf(wiB0[k], xc[p2 * 5 + k], pre1B);
#pragma unroll
    for (int k = 0; k < 5; ++k) pre1B = fmaf(whB0[k], h1a[p2 * 5 + k], pre1B);
    pre1B += __shfl_xor(pre1B, 16);
    pre1B += __shfl_xor(pre1B, 32);
    pre1B += bB0;

    float a1 = fmaf(actA, __builtin_amdgcn_rcpf(1.f + __expf(actB * pre1)), actC);
    float a1B = sigm(pre1B);

    float fv = __shfl(a1, (lane + 20) & 63);
    float gv = __shfl(a1, (lane + 40) & 63);
    float ov1 = __shfl(a1, (lane + 60) & 63);
    float ov2 = __shfl(a1B, (lane - 4) & 63);
    float ov = (lane < 4) ? ov1 : ov2;
    float cn1 = fmaf(fv, c1, a1 * gv);
    c1 = cn1;
    float h1j = ov * tanh_fast(cn1);
    if (lane < 20) hb[wave][0][lane] = h1j;
    __asm__ volatile("s_waitcnt lgkmcnt(0)" ::: "memory");
    LOAD20(h1a, &hb[wave][0][0]);

    // ---- L2 gates ----
    float u0 = bA1 + hh2, u1 = 0.f, u2 = 0.f, u3 = 0.f;
#pragma unroll
    for (int k = 0; k < 5; ++k) {
      u0 = fmaf(wiA1[4 * k + 0], h1a[4 * k + 0], u0);
      u1 = fmaf(wiA1[4 * k + 1], h1a[4 * k + 1], u1);
      u2 = fmaf(wiA1[4 * k + 2], h1a[4 * k + 2], u2);
      u3 = fmaf(wiA1[4 * k + 3], h1a[4 * k + 3], u3);
    }
    float pre2 = (u0 + u1) + (u2 + u3);
    float pre2B = hh2B;
#pragma unroll
    for (int k = 0; k < 5; ++k) pre2B = fmaf(wiB1[k], h1a[p2 * 5 + k], pre2B);
    pre2B += __shfl_xor(pre2B, 16);
    pre2B += __shfl_xor(pre2B, 32);
    pre2B += bB1;
    float a2 = fmaf(actA, __builtin_amdgcn_rcpf(1.f + __expf(actB * pre2)), actC);
    float a2B = sigm(pre2B);
    float fv2 = __shfl(a2, (lane + 20) & 63);
    float gv2 = __shfl(a2, (lane + 40) & 63);
    float ow1 = __shfl(a2, (lane + 60) & 63);
    float ow2 = __shfl(a2B, (lane - 4) & 63);
    float ow = (lane < 4) ? ow1 : ow2;
    float cn2 = fmaf(fv2, c2, a2 * gv2);
    c2 = cn2;
    float h2j = ow * tanh_fast(cn2);
    if (lane < 20) hb[wave][1][lane] = h2j;

    // prefetch next x column while h2 broadcast is in flight
    if (t < 256) {
      int f = (wave == 0) ? t : (255 - t);
      LOAD20(xc, tile + f * 20);
    }
    __asm__ volatile("s_waitcnt lgkmcnt(0)" ::: "memory");
    LOAD20(h2a, &hb[wave][1][0]);
  }

  __syncthreads();
  if (tid == 0) {
    float y = bv[0];
#pragma unroll
    for (int j = 0; j < 20; ++j) y = fmaf(Wv[j], hb[0][1][j], y);
#pragma unroll
    for (int j = 0; j < 20; ++j) y = fmaf(Wv[20 + j], hb[1][1][j], y);
    out[b] = y;
  }
}

extern "C" void kernel_launch(void* const* d_in, const int* in_sizes, int n_in,
                              void* d_out, int out_size, void* d_ws, size_t ws_size,
                              hipStream_t stream)
{
  const float* x    = (const float*)d_in[0];
  const float* W_N  = (const float*)d_in[1];
  const float* b_N  = (const float*)d_in[2];
  const float* W_up = (const float*)d_in[3];
  const float* b_up = (const float*)d_in[4];
  const float* mu   = (const float*)d_in[5];
  const float* Wih0 = (const float*)d_in[6];
  const float* Whh0 = (const float*)d_in[7];
  const float* bih0 = (const float*)d_in[8];
  const float* bhh0 = (const float*)d_in[9];
  const float* Wih1 = (const float*)d_in[10];
  const float* Whh1 = (const float*)d_in[11];
  const float* bih1 = (const float*)d_in[12];
  const float* bhh1 = (const float*)d_in[13];
  const float* Wv   = (const float*)d_in[14];
  const float* bvv  = (const float*)d_in[15];
  float* wsF = (float*)d_ws;
  float* xtp = wsF + WS_XT;
  float* outF = (float*)d_out;

  prep_kernel<<<41, 256, 0, stream>>>(W_N, b_N, W_up, b_up, wsF);
  xup_kernel<<<B_, 512, 0, stream>>>(x, wsF, xtp);
  lstm_kernel<<<B_, 128, 0, stream>>>(xtp, mu, Wih0, Whh0, bih0, bhh0,
                                      Wih1, Whh1, bih1, bhh1, Wv, bvv, outF);
}

// Round 2
// 248.484 us; speedup vs baseline: 2.0475x; 2.0475x over previous
//
#include <hip/hip_runtime.h>
#include <hip/hip_bf16.h>

#define B_ 256
#define S_ 512
#define F_ 256
#define L_ 20

// ws layout (floats): [0,10240) W_combT [512][20]; [10240,10260) b_comb; [16384, +B*F*20) x_t
#define WS_WCT 0
#define WS_BC  10240
#define WS_XT  16384

#define LOAD20(dst, ptr) { const float4* _p = (const float4*)(ptr); \
  float4 _a=_p[0], _b=_p[1], _c=_p[2], _d=_p[3], _e=_p[4]; \
  dst[0]=_a.x; dst[1]=_a.y; dst[2]=_a.z; dst[3]=_a.w; \
  dst[4]=_b.x; dst[5]=_b.y; dst[6]=_b.z; dst[7]=_b.w; \
  dst[8]=_c.x; dst[9]=_c.y; dst[10]=_c.z; dst[11]=_c.w; \
  dst[12]=_d.x; dst[13]=_d.y; dst[14]=_d.z; dst[15]=_d.w; \
  dst[16]=_e.x; dst[17]=_e.y; dst[18]=_e.z; dst[19]=_e.w; }

// ---------------- kernel 1: W_comb = W_up @ W_N (transposed store), b_comb ----------------
__global__ __launch_bounds__(256) void prep_kernel(
    const float* __restrict__ W_N, const float* __restrict__ b_N,
    const float* __restrict__ W_up, const float* __restrict__ b_up,
    float* __restrict__ wsF)
{
  int idx = blockIdx.x * 256 + threadIdx.x;
  if (idx < 10240) {
    int s = idx / 20, l = idx % 20;
    float acc = 0.f;
    for (int t = 0; t < S_; ++t)
      acc = fmaf(W_up[l * S_ + t], W_N[t * S_ + s], acc);
    wsF[WS_WCT + idx] = acc;          // W_combT[s][l]
  } else if (idx < 10260) {
    int j = idx - 10240;
    float acc = b_up[j];
    for (int t = 0; t < S_; ++t)
      acc = fmaf(W_up[j * S_ + t], b_N[t], acc);
    wsF[idx] = acc;                   // b_comb[j]
  }
}

// ---------------- kernel 2: x_t[b][f][l] = b_comb[l] + sum_s W_comb[l][s] * x[b][s][f] ----
__global__ __launch_bounds__(512) void xup_kernel(
    const float* __restrict__ x, const float* __restrict__ wsF,
    float* __restrict__ xt)
{
  __shared__ __align__(16) float Wl[10240];       // W_combT [512][20], 40KB
  __shared__ __align__(16) float part[F_ * L_];   // 20KB partials from p=1 half
  int b = blockIdx.x;
  int tid = threadIdx.x;
  {
    const float4* srcw = (const float4*)(wsF + WS_WCT);
    float4* dstw = (float4*)Wl;
    for (int i = tid; i < 10240 / 4; i += 512) dstw[i] = srcw[i];
  }
  __syncthreads();
  int f = tid & 255;
  int p = tid >> 8;                 // s-parity split across wave groups
  float acc[20];
#pragma unroll
  for (int l = 0; l < 20; ++l) acc[l] = 0.f;
  const float* xb = x + (size_t)b * S_ * F_ + f;
#pragma unroll 1
  for (int sg = 0; sg < S_; sg += 16) {
    float xv[8];
#pragma unroll
    for (int u = 0; u < 8; ++u) xv[u] = xb[(size_t)(sg + p + 2 * u) * F_];
#pragma unroll
    for (int u = 0; u < 8; ++u) {
      int s = sg + p + 2 * u;
      const float4* wp = (const float4*)(Wl + s * 20);
      float4 w0 = wp[0], w1 = wp[1], w2 = wp[2], w3 = wp[3], w4 = wp[4];
      acc[0] = fmaf(w0.x, xv[u], acc[0]);  acc[1] = fmaf(w0.y, xv[u], acc[1]);
      acc[2] = fmaf(w0.z, xv[u], acc[2]);  acc[3] = fmaf(w0.w, xv[u], acc[3]);
      acc[4] = fmaf(w1.x, xv[u], acc[4]);  acc[5] = fmaf(w1.y, xv[u], acc[5]);
      acc[6] = fmaf(w1.z, xv[u], acc[6]);  acc[7] = fmaf(w1.w, xv[u], acc[7]);
      acc[8] = fmaf(w2.x, xv[u], acc[8]);  acc[9] = fmaf(w2.y, xv[u], acc[9]);
      acc[10] = fmaf(w2.z, xv[u], acc[10]); acc[11] = fmaf(w2.w, xv[u], acc[11]);
      acc[12] = fmaf(w3.x, xv[u], acc[12]); acc[13] = fmaf(w3.y, xv[u], acc[13]);
      acc[14] = fmaf(w3.z, xv[u], acc[14]); acc[15] = fmaf(w3.w, xv[u], acc[15]);
      acc[16] = fmaf(w4.x, xv[u], acc[16]); acc[17] = fmaf(w4.y, xv[u], acc[17]);
      acc[18] = fmaf(w4.z, xv[u], acc[18]); acc[19] = fmaf(w4.w, xv[u], acc[19]);
    }
  }
  if (p == 1) {
#pragma unroll
    for (int l = 0; l < 20; ++l) part[f * 20 + l] = acc[l];
  }
  __syncthreads();
  if (p == 0) {
#pragma unroll
    for (int l = 0; l < 20; ++l) acc[l] += part[f * 20 + l] + wsF[WS_BC + l];
    float4* o = (float4*)(xt + ((size_t)b * F_ + f) * 20);
    o[0] = make_float4(acc[0], acc[1], acc[2], acc[3]);
    o[1] = make_float4(acc[4], acc[5], acc[6], acc[7]);
    o[2] = make_float4(acc[8], acc[9], acc[10], acc[11]);
    o[3] = make_float4(acc[12], acc[13], acc[14], acc[15]);
    o[4] = make_float4(acc[16], acc[17], acc[18], acc[19]);
  }
}

// ---------------- kernel 3: bidirectional 2-layer LSTM chain + final projection ----------
// Lane mapping per wave (one wave per chain):
//   lane l (0..63): "A" gate = W row l   (rows 0-19 = i_j, 20-39 = f_j, 40-59 = g_j, 60-63 = o_0..3, unused)
//   lane l: "B" gate = o-row 60 + (l % 20)  -- full 40-FMA dot, meaningful for l < 20
// Lane j<20 owns unit j: has i_j (A) and o_j (B); gathers f_j (lane 20+j), g_j (lane 40+j)
// via 2 parallel bpermutes; computes c_j, h_j; broadcasts h via LDS write+read.
// Layers are software-pipelined: iter t runs L1(t) and L2(t-1) concurrently (independent).
__device__ __forceinline__ float sigm(float x) {
  return __builtin_amdgcn_rcpf(1.f + __expf(-x));
}
__device__ __forceinline__ float tanh_fast(float x) {
  return fmaf(2.f, __builtin_amdgcn_rcpf(1.f + __expf(-2.f * x)), -1.f);
}

#define LAYER_DOTS(preA, preB, wiA, whA, wiB, whB, bA, bB, XIN, HIN) { \
  float s0_ = (bA), s1_ = 0.f, s2_ = 0.f, s3_ = 0.f; \
  float q0_ = (bB), q1_ = 0.f, q2_ = 0.f, q3_ = 0.f; \
  _Pragma("unroll") \
  for (int k = 0; k < 5; ++k) { \
    s0_ = fmaf(wiA[4*k+0], XIN[4*k+0], s0_); s1_ = fmaf(wiA[4*k+1], XIN[4*k+1], s1_); \
    s2_ = fmaf(wiA[4*k+2], XIN[4*k+2], s2_); s3_ = fmaf(wiA[4*k+3], XIN[4*k+3], s3_); \
    q0_ = fmaf(wiB[4*k+0], XIN[4*k+0], q0_); q1_ = fmaf(wiB[4*k+1], XIN[4*k+1], q1_); \
    q2_ = fmaf(wiB[4*k+2], XIN[4*k+2], q2_); q3_ = fmaf(wiB[4*k+3], XIN[4*k+3], q3_); \
  } \
  _Pragma("unroll") \
  for (int k = 0; k < 5; ++k) { \
    s0_ = fmaf(whA[4*k+0], HIN[4*k+0], s0_); s1_ = fmaf(whA[4*k+1], HIN[4*k+1], s1_); \
    s2_ = fmaf(whA[4*k+2], HIN[4*k+2], s2_); s3_ = fmaf(whA[4*k+3], HIN[4*k+3], s3_); \
    q0_ = fmaf(whB[4*k+0], HIN[4*k+0], q0_); q1_ = fmaf(whB[4*k+1], HIN[4*k+1], q1_); \
    q2_ = fmaf(whB[4*k+2], HIN[4*k+2], q2_); q3_ = fmaf(whB[4*k+3], HIN[4*k+3], q3_); \
  } \
  preA = (s0_ + s1_) + (s2_ + s3_); preB = (q0_ + q1_) + (q2_ + q3_); }

__global__ __launch_bounds__(128, 1) void lstm_kernel(
    const float* __restrict__ xt, const float* __restrict__ mu,
    const float* __restrict__ Wih0, const float* __restrict__ Whh0,
    const float* __restrict__ bih0, const float* __restrict__ bhh0,
    const float* __restrict__ Wih1, const float* __restrict__ Whh1,
    const float* __restrict__ bih1, const float* __restrict__ bhh1,
    const float* __restrict__ Wv, const float* __restrict__ bv,
    float* __restrict__ out)
{
  __shared__ __align__(16) float tile[F_ * L_];   // x_t[b] : [256][20]
  __shared__ __align__(16) float hb[2][2][20];    // [wave][layer][unit] broadcast
  int b = blockIdx.x;
  int tid = threadIdx.x;
  int wave = tid >> 6;      // 0 = fwd sample b, 1 = rev sample B+b
  int lane = tid & 63;
  {
    const float4* src = (const float4*)(xt + (size_t)b * F_ * L_);
    float4* dst = (float4*)tile;
#pragma unroll 1
    for (int i = tid; i < (F_ * L_) / 4; i += 128) dst[i] = src[i];
  }
  __syncthreads();

  int rA = lane;
  int jmod = lane % 20;
  int rB = 60 + jmod;
  int lf = (lane + 20) & 63;    // source lane for f_j
  int lg = (lane + 40) & 63;    // source lane for g_j

  float wiA0[20], whA0[20], wiA1[20], whA1[20];
  float wiB0[20], whB0[20], wiB1[20], whB1[20];
  LOAD20(wiA0, Wih0 + rA * 20); LOAD20(whA0, Whh0 + rA * 20);
  LOAD20(wiA1, Wih1 + rA * 20); LOAD20(whA1, Whh1 + rA * 20);
  LOAD20(wiB0, Wih0 + rB * 20); LOAD20(whB0, Whh0 + rB * 20);
  LOAD20(wiB1, Wih1 + rB * 20); LOAD20(whB1, Whh1 + rB * 20);

  float bA0c = bih0[rA] + bhh0[rA];
  float bA1c = bih1[rA] + bhh1[rA];
  float bB0c = bih0[rB] + bhh0[rB];
  float bB1c = bih1[rB] + bhh1[rB];
  int typ = rA / 20;                       // 0:i 1:f 2:g 3:(o junk)
  float actB = (typ == 2) ? -2.f : -1.f;
  float actA = (typ == 2) ? 2.f : 1.f;
  float actC = (typ == 2) ? -1.f : 0.f;

  float h1p[20], h2p[20], xc[20];
#pragma unroll
  for (int k = 0; k < 20; ++k) { h1p[k] = 0.f; h2p[k] = 0.f; xc[k] = mu[k]; }
  float c1 = 0.f, c2 = 0.f;

  // ---------------- prologue: L1 step t=0 ----------------
  {
    float preA1, preB1;
    LAYER_DOTS(preA1, preB1, wiA0, whA0, wiB0, whB0, bA0c, bB0c, xc, h1p);
    float aA1; aA1 = fmaf(actA, __builtin_amdgcn_rcpf(1.f + __expf(actB * preA1)), actC);
    float aB1 = sigm(preB1);
    float f1 = __shfl(aA1, lf);
    float g1 = __shfl(aA1, lg);
    c1 = fmaf(f1, c1, aA1 * g1);
    float h1j = aB1 * tanh_fast(c1);
    if (lane < 20) hb[wave][0][lane] = h1j;
    __asm__ volatile("s_waitcnt lgkmcnt(0)" ::: "memory");
    // prefetch x(1)
    { int fi = wave ? 255 : 0; LOAD20(xc, tile + fi * 20); }
    LOAD20(h1p, &hb[wave][0][0]);
  }

  // ---------------- main loop: iter t runs L1(t) and L2(t-1) ----------------
#pragma unroll 1
  for (int t = 1; t <= 256; ++t) {
    float preA1, preB1, preA2, preB2;
    // L2 step (t-1): consumes h1p = h1(t-1), h2p = h2(t-2)
    LAYER_DOTS(preA2, preB2, wiA1, whA1, wiB1, whB1, bA1c, bB1c, h1p, h2p);
    // L1 step t: consumes xc = x(t), h1p = h1(t-1)
    LAYER_DOTS(preA1, preB1, wiA0, whA0, wiB0, whB0, bA0c, bB0c, xc, h1p);

    float aA1 = fmaf(actA, __builtin_amdgcn_rcpf(1.f + __expf(actB * preA1)), actC);
    float aA2 = fmaf(actA, __builtin_amdgcn_rcpf(1.f + __expf(actB * preA2)), actC);
    float aB1 = sigm(preB1);
    float aB2 = sigm(preB2);

    float f1 = __shfl(aA1, lf);
    float g1 = __shfl(aA1, lg);
    float f2 = __shfl(aA2, lf);
    float g2 = __shfl(aA2, lg);

    c1 = fmaf(f1, c1, aA1 * g1);
    float h1j = aB1 * tanh_fast(c1);
    c2 = fmaf(f2, c2, aA2 * g2);
    float h2j = aB2 * tanh_fast(c2);

    if (lane < 20) { hb[wave][0][lane] = h1j; hb[wave][1][lane] = h2j; }
    __asm__ volatile("s_waitcnt lgkmcnt(0)" ::: "memory");
    if (t < 256) {                        // prefetch x(t+1)
      int fi = wave ? (255 - t) : t;
      LOAD20(xc, tile + fi * 20);
    }
    LOAD20(h1p, &hb[wave][0][0]);
    LOAD20(h2p, &hb[wave][1][0]);
  }

  // ---------------- epilogue: L2 step t=256 ----------------
  {
    float preA2, preB2;
    LAYER_DOTS(preA2, preB2, wiA1, whA1, wiB1, whB1, bA1c, bB1c, h1p, h2p);
    float aA2 = fmaf(actA, __builtin_amdgcn_rcpf(1.f + __expf(actB * preA2)), actC);
    float aB2 = sigm(preB2);
    float f2 = __shfl(aA2, lf);
    float g2 = __shfl(aA2, lg);
    c2 = fmaf(f2, c2, aA2 * g2);
    float h2j = aB2 * tanh_fast(c2);
    if (lane < 20) hb[wave][1][lane] = h2j;
  }

  __syncthreads();
  if (tid == 0) {
    float y = bv[0];
#pragma unroll
    for (int j = 0; j < 20; ++j) y = fmaf(Wv[j], hb[0][1][j], y);
#pragma unroll
    for (int j = 0; j < 20; ++j) y = fmaf(Wv[20 + j], hb[1][1][j], y);
    out[b] = y;
  }
}

extern "C" void kernel_launch(void* const* d_in, const int* in_sizes, int n_in,
                              void* d_out, int out_size, void* d_ws, size_t ws_size,
                              hipStream_t stream)
{
  const float* x    = (const float*)d_in[0];
  const float* W_N  = (const float*)d_in[1];
  const float* b_N  = (const float*)d_in[2];
  const float* W_up = (const float*)d_in[3];
  const float* b_up = (const float*)d_in[4];
  const float* mu   = (const float*)d_in[5];
  const float* Wih0 = (const float*)d_in[6];
  const float* Whh0 = (const float*)d_in[7];
  const float* bih0 = (const float*)d_in[8];
  const float* bhh0 = (const float*)d_in[9];
  const float* Wih1 = (const float*)d_in[10];
  const float* Whh1 = (const float*)d_in[11];
  const float* bih1 = (const float*)d_in[12];
  const float* bhh1 = (const float*)d_in[13];
  const float* Wv   = (const float*)d_in[14];
  const float* bvv  = (const float*)d_in[15];
  float* wsF = (float*)d_ws;
  float* xtp = wsF + WS_XT;
  float* outF = (float*)d_out;

  prep_kernel<<<41, 256, 0, stream>>>(W_N, b_N, W_up, b_up, wsF);
  xup_kernel<<<B_, 512, 0, stream>>>(x, wsF, xtp);
  lstm_kernel<<<B_, 128, 0, stream>>>(xtp, mu, Wih0, Whh0, bih0, bhh0,
                                      Wih1, Whh1, bih1, bhh1, Wv, bvv, outF);
}

// Round 3
// 233.829 us; speedup vs baseline: 2.1758x; 1.0627x over previous
//
#include <hip/hip_runtime.h>
#include <hip/hip_bf16.h>

#define B_ 256
#define S_ 512
#define F_ 256
#define L_ 20

// ws layout (floats):
//   [0,10240)      W_combT [512][20]
//   [10240,10260)  b_comb[20]
//   [10260,10340)  xw_mu[80]  = bih0+bhh0 + W_ih0·mu
//   [10340,10420)  bsum[80]   = bih0+bhh0
//   [16384, +256*256*80) xw0[b][f][80] = bsum + W_ih0·x_up[b][f][:]
#define WS_WCT 0
#define WS_BC  10240
#define WS_XWMU 10260
#define WS_BSUM 10340
#define WS_XW  16384

#define LOAD20(dst, ptr) { const float4* _p = (const float4*)(ptr); \
  float4 _a=_p[0], _b=_p[1], _c=_p[2], _d=_p[3], _e=_p[4]; \
  dst[0]=_a.x; dst[1]=_a.y; dst[2]=_a.z; dst[3]=_a.w; \
  dst[4]=_b.x; dst[5]=_b.y; dst[6]=_b.z; dst[7]=_b.w; \
  dst[8]=_c.x; dst[9]=_c.y; dst[10]=_c.z; dst[11]=_c.w; \
  dst[12]=_d.x; dst[13]=_d.y; dst[14]=_d.z; dst[15]=_d.w; \
  dst[16]=_e.x; dst[17]=_e.y; dst[18]=_e.z; dst[19]=_e.w; }

// ---------------- kernel 1: combined weights ----------------
__global__ __launch_bounds__(256) void prep_kernel(
    const float* __restrict__ W_N, const float* __restrict__ b_N,
    const float* __restrict__ W_up, const float* __restrict__ b_up,
    const float* __restrict__ mu, const float* __restrict__ Wih0,
    const float* __restrict__ bih0, const float* __restrict__ bhh0,
    float* __restrict__ wsF)
{
  int idx = blockIdx.x * 256 + threadIdx.x;
  if (idx < 10240) {
    int s = idx / 20, l = idx % 20;
    float acc = 0.f;
    for (int t = 0; t < S_; ++t)
      acc = fmaf(W_up[l * S_ + t], W_N[t * S_ + s], acc);
    wsF[WS_WCT + idx] = acc;          // W_combT[s][l]
  } else if (idx < 10260) {
    int j = idx - 10240;
    float acc = b_up[j];
    for (int t = 0; t < S_; ++t)
      acc = fmaf(W_up[j * S_ + t], b_N[t], acc);
    wsF[idx] = acc;                   // b_comb[j]
  } else if (idx < 10340) {
    int g = idx - 10260;
    float acc = bih0[g] + bhh0[g];
#pragma unroll
    for (int l = 0; l < 20; ++l) acc = fmaf(Wih0[g * 20 + l], mu[l], acc);
    wsF[WS_XWMU + g] = acc;           // xw_mu[g] (bias folded)
  } else if (idx < 10420) {
    int g = idx - 10340;
    wsF[WS_BSUM + g] = bih0[g] + bhh0[g];
  }
}

// ---------------- kernel 2: x -> x_up -> xw0 (L1 gate pre-projections) ----------------
__global__ __launch_bounds__(512) void xw_kernel(
    const float* __restrict__ x, const float* __restrict__ Wih0,
    const float* __restrict__ wsF, float* __restrict__ xw)
{
  __shared__ __align__(16) float Wl[10240];      // W_combT, 40KB
  __shared__ __align__(16) float xu[F_ * L_];    // x_up tile, 20KB
  __shared__ __align__(16) float Wg[80 * 20];    // W_ih0, 6.4KB
  __shared__ float bsumL[80];
  __shared__ float bcL[20];
  int b = blockIdx.x;
  int tid = threadIdx.x;
  {
    const float4* srcw = (const float4*)(wsF + WS_WCT);
    float4* dstw = (float4*)Wl;
    for (int i = tid; i < 2560; i += 512) dstw[i] = srcw[i];
    const float4* srcg = (const float4*)Wih0;
    float4* dstg = (float4*)Wg;
    for (int i = tid; i < 400; i += 512) dstg[i] = srcg[i];
    if (tid < 80) bsumL[tid] = wsF[WS_BSUM + tid];
    if (tid < 20) bcL[tid] = wsF[WS_BC + tid];
  }
  __syncthreads();
  int f = tid & 255;
  int p = tid >> 8;                 // s-parity split
  float acc[20];
#pragma unroll
  for (int l = 0; l < 20; ++l) acc[l] = 0.f;
  const float* xb = x + (size_t)b * S_ * F_ + f;
#pragma unroll 1
  for (int sg = 0; sg < S_; sg += 16) {
    float xv[8];
#pragma unroll
    for (int u = 0; u < 8; ++u) xv[u] = xb[(size_t)(sg + p + 2 * u) * F_];
#pragma unroll
    for (int u = 0; u < 8; ++u) {
      int s = sg + p + 2 * u;
      const float4* wp = (const float4*)(Wl + s * 20);
      float4 w0 = wp[0], w1 = wp[1], w2 = wp[2], w3 = wp[3], w4 = wp[4];
      acc[0] = fmaf(w0.x, xv[u], acc[0]);  acc[1] = fmaf(w0.y, xv[u], acc[1]);
      acc[2] = fmaf(w0.z, xv[u], acc[2]);  acc[3] = fmaf(w0.w, xv[u], acc[3]);
      acc[4] = fmaf(w1.x, xv[u], acc[4]);  acc[5] = fmaf(w1.y, xv[u], acc[5]);
      acc[6] = fmaf(w1.z, xv[u], acc[6]);  acc[7] = fmaf(w1.w, xv[u], acc[7]);
      acc[8] = fmaf(w2.x, xv[u], acc[8]);  acc[9] = fmaf(w2.y, xv[u], acc[9]);
      acc[10] = fmaf(w2.z, xv[u], acc[10]); acc[11] = fmaf(w2.w, xv[u], acc[11]);
      acc[12] = fmaf(w3.x, xv[u], acc[12]); acc[13] = fmaf(w3.y, xv[u], acc[13]);
      acc[14] = fmaf(w3.z, xv[u], acc[14]); acc[15] = fmaf(w3.w, xv[u], acc[15]);
      acc[16] = fmaf(w4.x, xv[u], acc[16]); acc[17] = fmaf(w4.y, xv[u], acc[17]);
      acc[18] = fmaf(w4.z, xv[u], acc[18]); acc[19] = fmaf(w4.w, xv[u], acc[19]);
    }
  }
  if (p == 1) {
#pragma unroll
    for (int l = 0; l < 20; ++l) xu[f * 20 + l] = acc[l];
  }
  __syncthreads();
  if (p == 0) {
#pragma unroll
    for (int l = 0; l < 20; ++l) xu[f * 20 + l] = acc[l] + xu[f * 20 + l] + bcL[l];
  }
  __syncthreads();
  // projection: thread (f2, half) computes gates [half*40, half*40+40)
  int f2 = tid >> 1, half = tid & 1;
  float xr[20];
  LOAD20(xr, xu + f2 * 20);
  float* ob = xw + ((size_t)b * 256 + f2) * 80 + half * 40;
  const float* wgbase = Wg + half * 40 * 20;
  const float* bsb = bsumL + half * 40;
#pragma unroll 2
  for (int g = 0; g < 40; ++g) {
    const float4* wp = (const float4*)(wgbase + g * 20);
    float4 w0 = wp[0], w1 = wp[1], w2 = wp[2], w3 = wp[3], w4 = wp[4];
    float a0 = bsb[g], a1 = 0.f, a2 = 0.f, a3 = 0.f;
    a0 = fmaf(w0.x, xr[0], a0);  a1 = fmaf(w0.y, xr[1], a1);
    a2 = fmaf(w0.z, xr[2], a2);  a3 = fmaf(w0.w, xr[3], a3);
    a0 = fmaf(w1.x, xr[4], a0);  a1 = fmaf(w1.y, xr[5], a1);
    a2 = fmaf(w1.z, xr[6], a2);  a3 = fmaf(w1.w, xr[7], a3);
    a0 = fmaf(w2.x, xr[8], a0);  a1 = fmaf(w2.y, xr[9], a1);
    a2 = fmaf(w2.z, xr[10], a2); a3 = fmaf(w2.w, xr[11], a3);
    a0 = fmaf(w3.x, xr[12], a0); a1 = fmaf(w3.y, xr[13], a1);
    a2 = fmaf(w3.z, xr[14], a2); a3 = fmaf(w3.w, xr[15], a3);
    a0 = fmaf(w4.x, xr[16], a0); a1 = fmaf(w4.y, xr[17], a1);
    a2 = fmaf(w4.z, xr[18], a2); a3 = fmaf(w4.w, xr[19], a3);
    ob[g] = (a0 + a1) + (a2 + a3);
  }
}

// ---------------- kernel 3: bidirectional 2-layer LSTM, readlane broadcast ----------
__device__ __forceinline__ float rlf(float v, int k) {
  return __int_as_float(__builtin_amdgcn_readlane(__float_as_int(v), k));
}
__device__ __forceinline__ float sigm(float x) {
  return __builtin_amdgcn_rcpf(1.f + __expf(-x));
}
__device__ __forceinline__ float tanh_fast(float x) {
  return fmaf(2.f, __builtin_amdgcn_rcpf(1.f + __expf(-2.f * x)), -1.f);
}

#define READ_H(dst, src) { \
  dst[0]=rlf(src,0);  dst[1]=rlf(src,1);  dst[2]=rlf(src,2);  dst[3]=rlf(src,3); \
  dst[4]=rlf(src,4);  dst[5]=rlf(src,5);  dst[6]=rlf(src,6);  dst[7]=rlf(src,7); \
  dst[8]=rlf(src,8);  dst[9]=rlf(src,9);  dst[10]=rlf(src,10); dst[11]=rlf(src,11); \
  dst[12]=rlf(src,12); dst[13]=rlf(src,13); dst[14]=rlf(src,14); dst[15]=rlf(src,15); \
  dst[16]=rlf(src,16); dst[17]=rlf(src,17); dst[18]=rlf(src,18); dst[19]=rlf(src,19); }

#define L2_DOTS(preA2, preB2) { \
  float u0 = bA1c, u1 = 0.f, u2 = 0.f, u3 = 0.f; \
  float v0 = bB1c, v1 = 0.f, v2 = 0.f, v3 = 0.f; \
  _Pragma("unroll") \
  for (int k = 0; k < 5; ++k) { \
    u0 = fmaf(wiA1[4*k+0], sh1[4*k+0], u0); u1 = fmaf(wiA1[4*k+1], sh1[4*k+1], u1); \
    u2 = fmaf(wiA1[4*k+2], sh1[4*k+2], u2); u3 = fmaf(wiA1[4*k+3], sh1[4*k+3], u3); \
    v0 = fmaf(wiB1[4*k+0], sh1[4*k+0], v0); v1 = fmaf(wiB1[4*k+1], sh1[4*k+1], v1); \
    v2 = fmaf(wiB1[4*k+2], sh1[4*k+2], v2); v3 = fmaf(wiB1[4*k+3], sh1[4*k+3], v3); \
  } \
  _Pragma("unroll") \
  for (int k = 0; k < 5; ++k) { \
    u0 = fmaf(whA1[4*k+0], sh2[4*k+0], u0); u1 = fmaf(whA1[4*k+1], sh2[4*k+1], u1); \
    u2 = fmaf(whA1[4*k+2], sh2[4*k+2], u2); u3 = fmaf(whA1[4*k+3], sh2[4*k+3], u3); \
    v0 = fmaf(whB1[4*k+0], sh2[4*k+0], v0); v1 = fmaf(whB1[4*k+1], sh2[4*k+1], v1); \
    v2 = fmaf(whB1[4*k+2], sh2[4*k+2], v2); v3 = fmaf(whB1[4*k+3], sh2[4*k+3], v3); \
  } \
  preA2 = (u0 + u1) + (u2 + u3); preB2 = (v0 + v1) + (v2 + v3); }

__global__ __launch_bounds__(128, 1) void lstm_kernel(
    const float* __restrict__ xw, const float* __restrict__ wsF,
    const float* __restrict__ Whh0,
    const float* __restrict__ Wih1, const float* __restrict__ Whh1,
    const float* __restrict__ bih1, const float* __restrict__ bhh1,
    const float* __restrict__ Wv, const float* __restrict__ bv,
    float* __restrict__ out)
{
  __shared__ float hb[2][20];
  int b = blockIdx.x;
  int tid = threadIdx.x;
  int wave = tid >> 6;      // 0 = fwd chain b, 1 = rev chain B+b
  int lane = tid & 63;
  int jmod = lane % 20;
  int rA = lane, rB = 60 + jmod;
  int lf = (lane + 20) & 63;
  int lg = (lane + 40) & 63;

  float whA0[20], whB0[20], wiA1[20], whA1[20], wiB1[20], whB1[20];
  LOAD20(whA0, Whh0 + rA * 20); LOAD20(whB0, Whh0 + rB * 20);
  LOAD20(wiA1, Wih1 + rA * 20); LOAD20(whA1, Whh1 + rA * 20);
  LOAD20(wiB1, Wih1 + rB * 20); LOAD20(whB1, Whh1 + rB * 20);
  float bA1c = bih1[rA] + bhh1[rA];
  float bB1c = bih1[rB] + bhh1[rB];

  int typ = lane / 20;
  float actB = (typ == 2) ? -2.f : -1.f;
  float actA = (typ == 2) ? 2.f : 1.f;
  float actC = (typ == 2) ? -1.f : 0.f;

  float sh1[20], sh2[20];
#pragma unroll
  for (int k = 0; k < 20; ++k) { sh1[k] = 0.f; sh2[k] = 0.f; }
  float c1 = 0.f, c2 = 0.f;

  const float* prow = xw + ((size_t)b * 256 + (wave ? 255 : 0)) * 80;
  int pstep = wave ? -80 : 80;

  // 2-deep prefetch: buf0 = row(t=1), buf1 = row(t=2)
  float xwA0v = prow[rA], xwB0v = prow[rB];
  prow += pstep;
  float xwA1v = prow[rA], xwB1v = prow[rB];

  // ---------------- prologue: L1 step 0 (input = mu projection, h=0) ----------------
  {
    float preA = wsF[WS_XWMU + rA];
    float preB = wsF[WS_XWMU + rB];
    float aA = fmaf(actA, __builtin_amdgcn_rcpf(1.f + __expf(actB * preA)), actC);
    float aB = sigm(preB);
    float g1v = __shfl(aA, lg);
    c1 = aA * g1v;                       // f*c0 = 0
    float h1j = aB * tanh_fast(c1);
    READ_H(sh1, h1j);
  }

  // ---------------- main loop: iter t runs L1(t) and L2(t-1) ----------------
#pragma unroll 1
  for (int t = 1; t <= 256; ++t) {
    float cxwA = xwA0v, cxwB = xwB0v;
    xwA0v = xwA1v; xwB0v = xwB1v;
    if (t <= 254) {                       // prefetch row(t+2)
      prow += pstep;
      xwA1v = prow[rA]; xwB1v = prow[rB];
    }

    float preA2, preB2;
    L2_DOTS(preA2, preB2);                // step t-1: sh1=h1(t-1), sh2=h2(t-2)

    // L1 dots (step t): input projection precomputed, h-part over sh1
    float a0 = cxwA, a1 = 0.f, a2 = 0.f, a3 = 0.f;
    float q0 = cxwB, q1 = 0.f, q2 = 0.f, q3 = 0.f;
#pragma unroll
    for (int k = 0; k < 5; ++k) {
      a0 = fmaf(whA0[4*k+0], sh1[4*k+0], a0); a1 = fmaf(whA0[4*k+1], sh1[4*k+1], a1);
      a2 = fmaf(whA0[4*k+2], sh1[4*k+2], a2); a3 = fmaf(whA0[4*k+3], sh1[4*k+3], a3);
      q0 = fmaf(whB0[4*k+0], sh1[4*k+0], q0); q1 = fmaf(whB0[4*k+1], sh1[4*k+1], q1);
      q2 = fmaf(whB0[4*k+2], sh1[4*k+2], q2); q3 = fmaf(whB0[4*k+3], sh1[4*k+3], q3);
    }
    float preA1 = (a0 + a1) + (a2 + a3);
    float preB1 = (q0 + q1) + (q2 + q3);

    float aA1 = fmaf(actA, __builtin_amdgcn_rcpf(1.f + __expf(actB * preA1)), actC);
    float aA2 = fmaf(actA, __builtin_amdgcn_rcpf(1.f + __expf(actB * preA2)), actC);
    float aB1 = sigm(preB1);
    float aB2 = sigm(preB2);

    float f1 = __shfl(aA1, lf);
    float g1v = __shfl(aA1, lg);
    float f2 = __shfl(aA2, lf);
    float g2v = __shfl(aA2, lg);

    c1 = fmaf(f1, c1, aA1 * g1v);
    float h1j = aB1 * tanh_fast(c1);
    c2 = fmaf(f2, c2, aA2 * g2v);
    float h2j = aB2 * tanh_fast(c2);

    READ_H(sh1, h1j);
    READ_H(sh2, h2j);
  }

  // ---------------- epilogue: L2 step 256 ----------------
  {
    float preA2, preB2;
    L2_DOTS(preA2, preB2);                // sh1=h1(256), sh2=h2(255)
    float aA2 = fmaf(actA, __builtin_amdgcn_rcpf(1.f + __expf(actB * preA2)), actC);
    float aB2 = sigm(preB2);
    float f2 = __shfl(aA2, lf);
    float g2v = __shfl(aA2, lg);
    c2 = fmaf(f2, c2, aA2 * g2v);
    float h2j = aB2 * tanh_fast(c2);
    if (lane < 20) hb[wave][lane] = h2j;
  }

  __syncthreads();
  if (tid == 0) {
    float y = bv[0];
#pragma unroll
    for (int j = 0; j < 20; ++j) y = fmaf(Wv[j], hb[0][j], y);
#pragma unroll
    for (int j = 0; j < 20; ++j) y = fmaf(Wv[20 + j], hb[1][j], y);
    out[b] = y;
  }
}

extern "C" void kernel_launch(void* const* d_in, const int* in_sizes, int n_in,
                              void* d_out, int out_size, void* d_ws, size_t ws_size,
                              hipStream_t stream)
{
  const float* x    = (const float*)d_in[0];
  const float* W_N  = (const float*)d_in[1];
  const float* b_N  = (const float*)d_in[2];
  const float* W_up = (const float*)d_in[3];
  const float* b_up = (const float*)d_in[4];
  const float* mu   = (const float*)d_in[5];
  const float* Wih0 = (const float*)d_in[6];
  const float* Whh0 = (const float*)d_in[7];
  const float* bih0 = (const float*)d_in[8];
  const float* bhh0 = (const float*)d_in[9];
  const float* Wih1 = (const float*)d_in[10];
  const float* Whh1 = (const float*)d_in[11];
  const float* bih1 = (const float*)d_in[12];
  const float* bhh1 = (const float*)d_in[13];
  const float* Wv   = (const float*)d_in[14];
  const float* bvv  = (const float*)d_in[15];
  float* wsF = (float*)d_ws;
  float* xwp = wsF + WS_XW;
  float* outF = (float*)d_out;

  prep_kernel<<<41, 256, 0, stream>>>(W_N, b_N, W_up, b_up, mu, Wih0, bih0, bhh0, wsF);
  xw_kernel<<<B_, 512, 0, stream>>>(x, Wih0, wsF, xwp);
  lstm_kernel<<<B_, 128, 0, stream>>>(xwp, wsF, Whh0, Wih1, Whh1,
                                      bih1, bhh1, Wv, bvv, outF);
}

// Round 4
// 202.640 us; speedup vs baseline: 2.5107x; 1.1539x over previous
//
#include <hip/hip_runtime.h>
#include <hip/hip_bf16.h>

#define B_ 256
#define S_ 512
#define F_ 256
#define L_ 20

// ws layout (floats):
//   [0,10240)      W_combT [512][20]
//   [10240,10260)  b_comb[20]
//   [10260,10340)  xw_mu[80]  = bih0+bhh0 + W_ih0·mu
//   [10340,10420)  bsum[80]   = bih0+bhh0
//   [16384, +256*256*80) xw0[b][f][80] = bsum + W_ih0·x_up[b][f][:]
#define WS_WCT 0
#define WS_BC  10240
#define WS_XWMU 10260
#define WS_BSUM 10340
#define WS_XW  16384

#define LOAD20(dst, ptr) { const float4* _p = (const float4*)(ptr); \
  float4 _a=_p[0], _b=_p[1], _c=_p[2], _d=_p[3], _e=_p[4]; \
  dst[0]=_a.x; dst[1]=_a.y; dst[2]=_a.z; dst[3]=_a.w; \
  dst[4]=_b.x; dst[5]=_b.y; dst[6]=_b.z; dst[7]=_b.w; \
  dst[8]=_c.x; dst[9]=_c.y; dst[10]=_c.z; dst[11]=_c.w; \
  dst[12]=_d.x; dst[13]=_d.y; dst[14]=_d.z; dst[15]=_d.w; \
  dst[16]=_e.x; dst[17]=_e.y; dst[18]=_e.z; dst[19]=_e.w; }

// ---------------- kernel 1: combined weights ----------------
__global__ __launch_bounds__(256) void prep_kernel(
    const float* __restrict__ W_N, const float* __restrict__ b_N,
    const float* __restrict__ W_up, const float* __restrict__ b_up,
    const float* __restrict__ mu, const float* __restrict__ Wih0,
    const float* __restrict__ bih0, const float* __restrict__ bhh0,
    float* __restrict__ wsF)
{
  int idx = blockIdx.x * 256 + threadIdx.x;
  if (idx < 10240) {
    int s = idx / 20, l = idx % 20;
    float acc = 0.f;
    for (int t = 0; t < S_; ++t)
      acc = fmaf(W_up[l * S_ + t], W_N[t * S_ + s], acc);
    wsF[WS_WCT + idx] = acc;          // W_combT[s][l]
  } else if (idx < 10260) {
    int j = idx - 10240;
    float acc = b_up[j];
    for (int t = 0; t < S_; ++t)
      acc = fmaf(W_up[j * S_ + t], b_N[t], acc);
    wsF[idx] = acc;                   // b_comb[j]
  } else if (idx < 10340) {
    int g = idx - 10260;
    float acc = bih0[g] + bhh0[g];
#pragma unroll
    for (int l = 0; l < 20; ++l) acc = fmaf(Wih0[g * 20 + l], mu[l], acc);
    wsF[WS_XWMU + g] = acc;           // xw_mu[g] (bias folded)
  } else if (idx < 10420) {
    int g = idx - 10340;
    wsF[WS_BSUM + g] = bih0[g] + bhh0[g];
  }
}

// ---------------- kernel 2: x -> x_up -> xw0 (L1 gate pre-projections) ----------------
__global__ __launch_bounds__(512) void xw_kernel(
    const float* __restrict__ x, const float* __restrict__ Wih0,
    const float* __restrict__ wsF, float* __restrict__ xw)
{
  __shared__ __align__(16) float Wl[10240];      // W_combT, 40KB
  __shared__ __align__(16) float xu[F_ * L_];    // x_up tile, 20KB
  __shared__ __align__(16) float Wg[80 * 20];    // W_ih0, 6.4KB
  __shared__ float bsumL[80];
  __shared__ float bcL[20];
  int b = blockIdx.x;
  int tid = threadIdx.x;
  {
    const float4* srcw = (const float4*)(wsF + WS_WCT);
    float4* dstw = (float4*)Wl;
    for (int i = tid; i < 2560; i += 512) dstw[i] = srcw[i];
    const float4* srcg = (const float4*)Wih0;
    float4* dstg = (float4*)Wg;
    for (int i = tid; i < 400; i += 512) dstg[i] = srcg[i];
    if (tid < 80) bsumL[tid] = wsF[WS_BSUM + tid];
    if (tid < 20) bcL[tid] = wsF[WS_BC + tid];
  }
  __syncthreads();
  int f = tid & 255;
  int p = tid >> 8;                 // s-parity split
  float acc[20];
#pragma unroll
  for (int l = 0; l < 20; ++l) acc[l] = 0.f;
  const float* xb = x + (size_t)b * S_ * F_ + f;
#pragma unroll 1
  for (int sg = 0; sg < S_; sg += 16) {
    float xv[8];
#pragma unroll
    for (int u = 0; u < 8; ++u) xv[u] = xb[(size_t)(sg + p + 2 * u) * F_];
#pragma unroll
    for (int u = 0; u < 8; ++u) {
      int s = sg + p + 2 * u;
      const float4* wp = (const float4*)(Wl + s * 20);
      float4 w0 = wp[0], w1 = wp[1], w2 = wp[2], w3 = wp[3], w4 = wp[4];
      acc[0] = fmaf(w0.x, xv[u], acc[0]);  acc[1] = fmaf(w0.y, xv[u], acc[1]);
      acc[2] = fmaf(w0.z, xv[u], acc[2]);  acc[3] = fmaf(w0.w, xv[u], acc[3]);
      acc[4] = fmaf(w1.x, xv[u], acc[4]);  acc[5] = fmaf(w1.y, xv[u], acc[5]);
      acc[6] = fmaf(w1.z, xv[u], acc[6]);  acc[7] = fmaf(w1.w, xv[u], acc[7]);
      acc[8] = fmaf(w2.x, xv[u], acc[8]);  acc[9] = fmaf(w2.y, xv[u], acc[9]);
      acc[10] = fmaf(w2.z, xv[u], acc[10]); acc[11] = fmaf(w2.w, xv[u], acc[11]);
      acc[12] = fmaf(w3.x, xv[u], acc[12]); acc[13] = fmaf(w3.y, xv[u], acc[13]);
      acc[14] = fmaf(w3.z, xv[u], acc[14]); acc[15] = fmaf(w3.w, xv[u], acc[15]);
      acc[16] = fmaf(w4.x, xv[u], acc[16]); acc[17] = fmaf(w4.y, xv[u], acc[17]);
      acc[18] = fmaf(w4.z, xv[u], acc[18]); acc[19] = fmaf(w4.w, xv[u], acc[19]);
    }
  }
  if (p == 1) {
#pragma unroll
    for (int l = 0; l < 20; ++l) xu[f * 20 + l] = acc[l];
  }
  __syncthreads();
  if (p == 0) {
#pragma unroll
    for (int l = 0; l < 20; ++l) xu[f * 20 + l] = acc[l] + xu[f * 20 + l] + bcL[l];
  }
  __syncthreads();
  // projection: thread (f2, half) computes gates [half*40, half*40+40)
  int f2 = tid >> 1, half = tid & 1;
  float xr[20];
  LOAD20(xr, xu + f2 * 20);
  float* ob = xw + ((size_t)b * 256 + f2) * 80 + half * 40;
  const float* wgbase = Wg + half * 40 * 20;
  const float* bsb = bsumL + half * 40;
#pragma unroll 2
  for (int g = 0; g < 40; ++g) {
    const float4* wp = (const float4*)(wgbase + g * 20);
    float4 w0 = wp[0], w1 = wp[1], w2 = wp[2], w3 = wp[3], w4 = wp[4];
    float a0 = bsb[g], a1 = 0.f, a2 = 0.f, a3 = 0.f;
    a0 = fmaf(w0.x, xr[0], a0);  a1 = fmaf(w0.y, xr[1], a1);
    a2 = fmaf(w0.z, xr[2], a2);  a3 = fmaf(w0.w, xr[3], a3);
    a0 = fmaf(w1.x, xr[4], a0);  a1 = fmaf(w1.y, xr[5], a1);
    a2 = fmaf(w1.z, xr[6], a2);  a3 = fmaf(w1.w, xr[7], a3);
    a0 = fmaf(w2.x, xr[8], a0);  a1 = fmaf(w2.y, xr[9], a1);
    a2 = fmaf(w2.z, xr[10], a2); a3 = fmaf(w2.w, xr[11], a3);
    a0 = fmaf(w3.x, xr[12], a0); a1 = fmaf(w3.y, xr[13], a1);
    a2 = fmaf(w3.z, xr[14], a2); a3 = fmaf(w3.w, xr[15], a3);
    a0 = fmaf(w4.x, xr[16], a0); a1 = fmaf(w4.y, xr[17], a1);
    a2 = fmaf(w4.z, xr[18], a2); a3 = fmaf(w4.w, xr[19], a3);
    ob[g] = (a0 + a1) + (a2 + a3);
  }
}

// ---------------- kernel 3: producer/consumer 2-wave LSTM per chain ----------
// Block = 256 threads = 4 waves = 2 chains (fwd b, rev B+b), 2 waves per chain:
//   role0 wave: L1 recurrence + L2 input projection xp2 = b1 + Wih1·h1
//   role1 wave: L2 recurrence  pre2 = xp2 + Whh1·h2
// Handoff: xp2 via LDS, parity double-buffered; one __syncthreads per step.
// Both role paths execute IDENTICAL barrier counts (counting-barrier pairing).
__device__ __forceinline__ float rlf(float v, int k) {
  return __int_as_float(__builtin_amdgcn_readlane(__float_as_int(v), k));
}
__device__ __forceinline__ float sigm(float x) {
  return __builtin_amdgcn_rcpf(1.f + __expf(-x));
}
__device__ __forceinline__ float tanh_fast(float x) {
  return fmaf(2.f, __builtin_amdgcn_rcpf(1.f + __expf(-2.f * x)), -1.f);
}

#define READ_H(dst, src) { \
  dst[0]=rlf(src,0);  dst[1]=rlf(src,1);  dst[2]=rlf(src,2);  dst[3]=rlf(src,3); \
  dst[4]=rlf(src,4);  dst[5]=rlf(src,5);  dst[6]=rlf(src,6);  dst[7]=rlf(src,7); \
  dst[8]=rlf(src,8);  dst[9]=rlf(src,9);  dst[10]=rlf(src,10); dst[11]=rlf(src,11); \
  dst[12]=rlf(src,12); dst[13]=rlf(src,13); dst[14]=rlf(src,14); dst[15]=rlf(src,15); \
  dst[16]=rlf(src,16); dst[17]=rlf(src,17); dst[18]=rlf(src,18); dst[19]=rlf(src,19); }

__global__ __launch_bounds__(256, 1) void lstm_kernel(
    const float* __restrict__ xw, const float* __restrict__ wsF,
    const float* __restrict__ Whh0,
    const float* __restrict__ Wih1, const float* __restrict__ Whh1,
    const float* __restrict__ bih1, const float* __restrict__ bhh1,
    const float* __restrict__ Wv, const float* __restrict__ bv,
    float* __restrict__ out)
{
  __shared__ float xpbuf[2][2][128];   // [chain][slot][xpA(64) | xpB(64)]
  __shared__ float hb[2][20];
  int b = blockIdx.x;
  int tid = threadIdx.x;
  int wid = tid >> 6;
  int lane = tid & 63;
  int chain = wid >> 1;      // 0 = fwd chain b, 1 = rev chain B+b
  int role = wid & 1;        // 0 = producer (L1), 1 = consumer (L2)
  int jmod = lane % 20;
  int rA = lane, rB = 60 + jmod;
  int lf = (lane + 20) & 63;
  int lg = (lane + 40) & 63;
  int typ = lane / 20;
  float actB = (typ == 2) ? -2.f : -1.f;
  float actA = (typ == 2) ? 2.f : 1.f;
  float actC = (typ == 2) ? -1.f : 0.f;

  if (role == 0) {
    // ---------------- producer: L1 + xp2 projection ----------------
    float whA0[20], whB0[20], wiA1[20], wiB1[20];
    LOAD20(whA0, Whh0 + rA * 20); LOAD20(whB0, Whh0 + rB * 20);
    LOAD20(wiA1, Wih1 + rA * 20); LOAD20(wiB1, Wih1 + rB * 20);
    float bA1c = bih1[rA] + bhh1[rA];
    float bB1c = bih1[rB] + bhh1[rB];

    float sh1[20];
    float c1;
    const float* prow = xw + ((size_t)b * 256 + (chain ? 255 : 0)) * 80;
    int pstep = chain ? -80 : 80;
    float xwA0v = prow[rA], xwB0v = prow[rB];
    prow += pstep;
    float xwA1v = prow[rA], xwB1v = prow[rB];

    // L1 step 0 (input = mu projection, h=c=0)
    {
      float preA = wsF[WS_XWMU + rA];
      float preB = wsF[WS_XWMU + rB];
      float aA = fmaf(actA, __builtin_amdgcn_rcpf(1.f + __expf(actB * preA)), actC);
      float aB = sigm(preB);
      float gv = __shfl(aA, lg);
      c1 = aA * gv;
      float h1j = aB * tanh_fast(c1);
      READ_H(sh1, h1j);
    }

#pragma unroll 1
    for (int i = 1; i <= 258; ++i) {
      __syncthreads();
      if (i <= 257) {
        // xp2(i-1) = b1 + Wih1·h1(i-1)  (sh1 currently holds h1(i-1))
        float xA0 = bA1c, xA1 = 0.f, xA2 = 0.f, xA3 = 0.f;
        float xB0 = bB1c, xB1 = 0.f, xB2 = 0.f, xB3 = 0.f;
#pragma unroll
        for (int k = 0; k < 5; ++k) {
          xA0 = fmaf(wiA1[4*k+0], sh1[4*k+0], xA0); xA1 = fmaf(wiA1[4*k+1], sh1[4*k+1], xA1);
          xA2 = fmaf(wiA1[4*k+2], sh1[4*k+2], xA2); xA3 = fmaf(wiA1[4*k+3], sh1[4*k+3], xA3);
          xB0 = fmaf(wiB1[4*k+0], sh1[4*k+0], xB0); xB1 = fmaf(wiB1[4*k+1], sh1[4*k+1], xB1);
          xB2 = fmaf(wiB1[4*k+2], sh1[4*k+2], xB2); xB3 = fmaf(wiB1[4*k+3], sh1[4*k+3], xB3);
        }
        int slot = (i - 1) & 1;
        xpbuf[chain][slot][lane]      = (xA0 + xA1) + (xA2 + xA3);
        xpbuf[chain][slot][64 + lane] = (xB0 + xB1) + (xB2 + xB3);
      }
      if (i <= 256) {
        // L1 step i: pre = xw(i) + Whh0·h1(i-1)
        float cxwA = xwA0v, cxwB = xwB0v;
        xwA0v = xwA1v; xwB0v = xwB1v;
        if (i <= 254) {
          prow += pstep;
          xwA1v = prow[rA]; xwB1v = prow[rB];
        }
        float a0 = cxwA, a1 = 0.f, a2 = 0.f, a3 = 0.f;
        float q0 = cxwB, q1 = 0.f, q2 = 0.f, q3 = 0.f;
#pragma unroll
        for (int k = 0; k < 5; ++k) {
          a0 = fmaf(whA0[4*k+0], sh1[4*k+0], a0); a1 = fmaf(whA0[4*k+1], sh1[4*k+1], a1);
          a2 = fmaf(whA0[4*k+2], sh1[4*k+2], a2); a3 = fmaf(whA0[4*k+3], sh1[4*k+3], a3);
          q0 = fmaf(whB0[4*k+0], sh1[4*k+0], q0); q1 = fmaf(whB0[4*k+1], sh1[4*k+1], q1);
          q2 = fmaf(whB0[4*k+2], sh1[4*k+2], q2); q3 = fmaf(whB0[4*k+3], sh1[4*k+3], q3);
        }
        float preA = (a0 + a1) + (a2 + a3);
        float preB = (q0 + q1) + (q2 + q3);
        float aA = fmaf(actA, __builtin_amdgcn_rcpf(1.f + __expf(actB * preA)), actC);
        float aB = sigm(preB);
        float fv = __shfl(aA, lf);
        float gv = __shfl(aA, lg);
        c1 = fmaf(fv, c1, aA * gv);
        float h1j = aB * tanh_fast(c1);
        READ_H(sh1, h1j);
      }
    }
  } else {
    // ---------------- consumer: L2 recurrence ----------------
    float whA1[20], whB1[20];
    LOAD20(whA1, Whh1 + rA * 20); LOAD20(whB1, Whh1 + rB * 20);
    float sh2[20];
#pragma unroll
    for (int k = 0; k < 20; ++k) sh2[k] = 0.f;
    float c2 = 0.f;

#pragma unroll 1
    for (int i = 1; i <= 258; ++i) {
      __syncthreads();
      if (i >= 2) {
        // L2 step (i-2): pre = xp2(i-2) + Whh1·h2(i-3); slot parity (i-2)&1 == i&1
        int slot = i & 1;
        float xpA = xpbuf[chain][slot][lane];
        float xpB = xpbuf[chain][slot][64 + lane];
        float u0 = 0.f, u1 = 0.f, u2 = 0.f, u3 = 0.f;
        float v0 = 0.f, v1 = 0.f, v2 = 0.f, v3 = 0.f;
#pragma unroll
        for (int k = 0; k < 5; ++k) {
          u0 = fmaf(whA1[4*k+0], sh2[4*k+0], u0); u1 = fmaf(whA1[4*k+1], sh2[4*k+1], u1);
          u2 = fmaf(whA1[4*k+2], sh2[4*k+2], u2); u3 = fmaf(whA1[4*k+3], sh2[4*k+3], u3);
          v0 = fmaf(whB1[4*k+0], sh2[4*k+0], v0); v1 = fmaf(whB1[4*k+1], sh2[4*k+1], v1);
          v2 = fmaf(whB1[4*k+2], sh2[4*k+2], v2); v3 = fmaf(whB1[4*k+3], sh2[4*k+3], v3);
        }
        float preA = ((u0 + u1) + (u2 + u3)) + xpA;
        float preB = ((v0 + v1) + (v2 + v3)) + xpB;
        float aA = fmaf(actA, __builtin_amdgcn_rcpf(1.f + __expf(actB * preA)), actC);
        float aB = sigm(preB);
        float fv = __shfl(aA, lf);
        float gv = __shfl(aA, lg);
        c2 = fmaf(fv, c2, aA * gv);
        float h2j = aB * tanh_fast(c2);
        if (lane < 20) hb[chain][lane] = h2j;
        READ_H(sh2, h2j);
      }
    }
  }

  __syncthreads();
  if (tid == 0) {
    float y = bv[0];
#pragma unroll
    for (int j = 0; j < 20; ++j) y = fmaf(Wv[j], hb[0][j], y);
#pragma unroll
    for (int j = 0; j < 20; ++j) y = fmaf(Wv[20 + j], hb[1][j], y);
    out[b] = y;
  }
}

extern "C" void kernel_launch(void* const* d_in, const int* in_sizes, int n_in,
                              void* d_out, int out_size, void* d_ws, size_t ws_size,
                              hipStream_t stream)
{
  const float* x    = (const float*)d_in[0];
  const float* W_N  = (const float*)d_in[1];
  const float* b_N  = (const float*)d_in[2];
  const float* W_up = (const float*)d_in[3];
  const float* b_up = (const float*)d_in[4];
  const float* mu   = (const float*)d_in[5];
  const float* Wih0 = (const float*)d_in[6];
  const float* Whh0 = (const float*)d_in[7];
  const float* bih0 = (const float*)d_in[8];
  const float* bhh0 = (const float*)d_in[9];
  const float* Wih1 = (const float*)d_in[10];
  const float* Whh1 = (const float*)d_in[11];
  const float* bih1 = (const float*)d_in[12];
  const float* bhh1 = (const float*)d_in[13];
  const float* Wv   = (const float*)d_in[14];
  const float* bvv  = (const float*)d_in[15];
  float* wsF = (float*)d_ws;
  float* xwp = wsF + WS_XW;
  float* outF = (float*)d_out;

  prep_kernel<<<41, 256, 0, stream>>>(W_N, b_N, W_up, b_up, mu, Wih0, bih0, bhh0, wsF);
  xw_kernel<<<B_, 512, 0, stream>>>(x, Wih0, wsF, xwp);
  lstm_kernel<<<B_, 256, 0, stream>>>(xwp, wsF, Whh0, Wih1, Whh1,
                                      bih1, bhh1, Wv, bvv, outF);
}

// Round 5
// 192.515 us; speedup vs baseline: 2.6427x; 1.0526x over previous
//
#include <hip/hip_runtime.h>
#include <hip/hip_bf16.h>

#define B_ 256
#define S_ 512
#define F_ 256
#define L_ 20

// ws layout (floats):
//   [0,10240)      W_combT [512][20]
//   [10240,10260)  b_comb[20]
//   [10260,10340)  xw_mu[80]  = bih0+bhh0 + W_ih0·mu
//   [10340,10420)  bsum[80]   = bih0+bhh0
//   [16384, +256*256*80) xw0[b][f][80] = bsum + W_ih0·x_up[b][f][:]
#define WS_WCT 0
#define WS_BC  10240
#define WS_XWMU 10260
#define WS_BSUM 10340
#define WS_XW  16384

#define LOAD20(dst, ptr) { const float4* _p = (const float4*)(ptr); \
  float4 _a=_p[0], _b=_p[1], _c=_p[2], _d=_p[3], _e=_p[4]; \
  dst[0]=_a.x; dst[1]=_a.y; dst[2]=_a.z; dst[3]=_a.w; \
  dst[4]=_b.x; dst[5]=_b.y; dst[6]=_b.z; dst[7]=_b.w; \
  dst[8]=_c.x; dst[9]=_c.y; dst[10]=_c.z; dst[11]=_c.w; \
  dst[12]=_d.x; dst[13]=_d.y; dst[14]=_d.z; dst[15]=_d.w; \
  dst[16]=_e.x; dst[17]=_e.y; dst[18]=_e.z; dst[19]=_e.w; }

// Pin a 20-float array into VGPRs at this program point (defeats in-loop remat).
#define PIN20(a) asm volatile("" \
  : "+v"(a[0]), "+v"(a[1]), "+v"(a[2]), "+v"(a[3]), "+v"(a[4]), \
    "+v"(a[5]), "+v"(a[6]), "+v"(a[7]), "+v"(a[8]), "+v"(a[9]), \
    "+v"(a[10]), "+v"(a[11]), "+v"(a[12]), "+v"(a[13]), "+v"(a[14]), \
    "+v"(a[15]), "+v"(a[16]), "+v"(a[17]), "+v"(a[18]), "+v"(a[19]))

// ---------------- kernel 1a: W_combT columns + b_comb (block 512) ----------------
__global__ __launch_bounds__(256) void prep_cols_kernel(
    const float* __restrict__ W_N, const float* __restrict__ b_N,
    const float* __restrict__ W_up, const float* __restrict__ b_up,
    float* __restrict__ wsF)
{
  __shared__ float wn[512];
  int s = blockIdx.x;                 // 0..511 -> column s; 512 -> b_comb
  int tid = threadIdx.x;
  bool isb = (s == 512);
  if (isb) {
    wn[tid] = b_N[tid];
    wn[tid + 256] = b_N[tid + 256];
  } else {
    wn[tid] = W_N[(size_t)tid * S_ + s];
    wn[tid + 256] = W_N[(size_t)(tid + 256) * S_ + s];
  }
  __syncthreads();
  int w = tid >> 6, lane = tid & 63;
#pragma unroll
  for (int li = 0; li < 5; ++li) {
    int l = w * 5 + li;
    const float* wu = W_up + (size_t)l * S_;
    float acc = 0.f;
#pragma unroll
    for (int j = 0; j < 8; ++j)
      acc = fmaf(wu[lane + 64 * j], wn[lane + 64 * j], acc);
    acc += __shfl_xor(acc, 1);  acc += __shfl_xor(acc, 2);
    acc += __shfl_xor(acc, 4);  acc += __shfl_xor(acc, 8);
    acc += __shfl_xor(acc, 16); acc += __shfl_xor(acc, 32);
    if (lane == 0) {
      if (isb) wsF[WS_BC + l] = acc + b_up[l];
      else     wsF[WS_WCT + s * 20 + l] = acc;
    }
  }
}

// ---------------- kernel 1b: xw_mu + bsum ----------------
__global__ __launch_bounds__(128) void prep_mu_kernel(
    const float* __restrict__ mu, const float* __restrict__ Wih0,
    const float* __restrict__ bih0, const float* __restrict__ bhh0,
    float* __restrict__ wsF)
{
  int tid = threadIdx.x;
  if (tid < 80) {
    float bs = bih0[tid] + bhh0[tid];
    wsF[WS_BSUM + tid] = bs;
    float acc = bs;
#pragma unroll
    for (int l = 0; l < 20; ++l) acc = fmaf(Wih0[tid * 20 + l], mu[l], acc);
    wsF[WS_XWMU + tid] = acc;
  }
}

// ---------------- kernel 2: x -> x_up -> xw0 (L1 gate pre-projections) ----------------
__global__ __launch_bounds__(512) void xw_kernel(
    const float* __restrict__ x, const float* __restrict__ Wih0,
    const float* __restrict__ wsF, float* __restrict__ xw)
{
  __shared__ __align__(16) float Wl[10240];      // W_combT, 40KB
  __shared__ __align__(16) float xu[F_ * L_];    // x_up tile, 20KB
  __shared__ __align__(16) float Wg[80 * 20];    // W_ih0, 6.4KB
  __shared__ float bsumL[80];
  __shared__ float bcL[20];
  int b = blockIdx.x;
  int tid = threadIdx.x;
  {
    const float4* srcw = (const float4*)(wsF + WS_WCT);
    float4* dstw = (float4*)Wl;
    for (int i = tid; i < 2560; i += 512) dstw[i] = srcw[i];
    const float4* srcg = (const float4*)Wih0;
    float4* dstg = (float4*)Wg;
    for (int i = tid; i < 400; i += 512) dstg[i] = srcg[i];
    if (tid < 80) bsumL[tid] = wsF[WS_BSUM + tid];
    if (tid < 20) bcL[tid] = wsF[WS_BC + tid];
  }
  __syncthreads();
  int f = tid & 255;
  int p = tid >> 8;                 // s-parity split
  float acc[20];
#pragma unroll
  for (int l = 0; l < 20; ++l) acc[l] = 0.f;
  const float* xb = x + (size_t)b * S_ * F_ + f;
#pragma unroll 1
  for (int sg = 0; sg < S_; sg += 16) {
    float xv[8];
#pragma unroll
    for (int u = 0; u < 8; ++u) xv[u] = xb[(size_t)(sg + p + 2 * u) * F_];
#pragma unroll
    for (int u = 0; u < 8; ++u) {
      int s = sg + p + 2 * u;
      const float4* wp = (const float4*)(Wl + s * 20);
      float4 w0 = wp[0], w1 = wp[1], w2 = wp[2], w3 = wp[3], w4 = wp[4];
      acc[0] = fmaf(w0.x, xv[u], acc[0]);  acc[1] = fmaf(w0.y, xv[u], acc[1]);
      acc[2] = fmaf(w0.z, xv[u], acc[2]);  acc[3] = fmaf(w0.w, xv[u], acc[3]);
      acc[4] = fmaf(w1.x, xv[u], acc[4]);  acc[5] = fmaf(w1.y, xv[u], acc[5]);
      acc[6] = fmaf(w1.z, xv[u], acc[6]);  acc[7] = fmaf(w1.w, xv[u], acc[7]);
      acc[8] = fmaf(w2.x, xv[u], acc[8]);  acc[9] = fmaf(w2.y, xv[u], acc[9]);
      acc[10] = fmaf(w2.z, xv[u], acc[10]); acc[11] = fmaf(w2.w, xv[u], acc[11]);
      acc[12] = fmaf(w3.x, xv[u], acc[12]); acc[13] = fmaf(w3.y, xv[u], acc[13]);
      acc[14] = fmaf(w3.z, xv[u], acc[14]); acc[15] = fmaf(w3.w, xv[u], acc[15]);
      acc[16] = fmaf(w4.x, xv[u], acc[16]); acc[17] = fmaf(w4.y, xv[u], acc[17]);
      acc[18] = fmaf(w4.z, xv[u], acc[18]); acc[19] = fmaf(w4.w, xv[u], acc[19]);
    }
  }
  if (p == 1) {
#pragma unroll
    for (int l = 0; l < 20; ++l) xu[f * 20 + l] = acc[l];
  }
  __syncthreads();
  if (p == 0) {
#pragma unroll
    for (int l = 0; l < 20; ++l) xu[f * 20 + l] = acc[l] + xu[f * 20 + l] + bcL[l];
  }
  __syncthreads();
  // projection: thread (f2, half) computes gates [half*40, half*40+40)
  int f2 = tid >> 1, half = tid & 1;
  float xr[20];
  LOAD20(xr, xu + f2 * 20);
  float* ob = xw + ((size_t)b * 256 + f2) * 80 + half * 40;
  const float* wgbase = Wg + half * 40 * 20;
  const float* bsb = bsumL + half * 40;
#pragma unroll 2
  for (int g = 0; g < 40; ++g) {
    const float4* wp = (const float4*)(wgbase + g * 20);
    float4 w0 = wp[0], w1 = wp[1], w2 = wp[2], w3 = wp[3], w4 = wp[4];
    float a0 = bsb[g], a1 = 0.f, a2 = 0.f, a3 = 0.f;
    a0 = fmaf(w0.x, xr[0], a0);  a1 = fmaf(w0.y, xr[1], a1);
    a2 = fmaf(w0.z, xr[2], a2);  a3 = fmaf(w0.w, xr[3], a3);
    a0 = fmaf(w1.x, xr[4], a0);  a1 = fmaf(w1.y, xr[5], a1);
    a2 = fmaf(w1.z, xr[6], a2);  a3 = fmaf(w1.w, xr[7], a3);
    a0 = fmaf(w2.x, xr[8], a0);  a1 = fmaf(w2.y, xr[9], a1);
    a2 = fmaf(w2.z, xr[10], a2); a3 = fmaf(w2.w, xr[11], a3);
    a0 = fmaf(w3.x, xr[12], a0); a1 = fmaf(w3.y, xr[13], a1);
    a2 = fmaf(w3.z, xr[14], a2); a3 = fmaf(w3.w, xr[15], a3);
    a0 = fmaf(w4.x, xr[16], a0); a1 = fmaf(w4.y, xr[17], a1);
    a2 = fmaf(w4.z, xr[18], a2); a3 = fmaf(w4.w, xr[19], a3);
    ob[g] = (a0 + a1) + (a2 + a3);
  }
}

// ---------------- kernel 3: producer/consumer 2-wave LSTM per chain ----------
__device__ __forceinline__ float rlf(float v, int k) {
  return __int_as_float(__builtin_amdgcn_readlane(__float_as_int(v), k));
}
__device__ __forceinline__ float sigm(float x) {
  return __builtin_amdgcn_rcpf(1.f + __expf(-x));
}
__device__ __forceinline__ float tanh_fast(float x) {
  return fmaf(2.f, __builtin_amdgcn_rcpf(1.f + __expf(-2.f * x)), -1.f);
}

#define READ_H(dst, src) { \
  dst[0]=rlf(src,0);  dst[1]=rlf(src,1);  dst[2]=rlf(src,2);  dst[3]=rlf(src,3); \
  dst[4]=rlf(src,4);  dst[5]=rlf(src,5);  dst[6]=rlf(src,6);  dst[7]=rlf(src,7); \
  dst[8]=rlf(src,8);  dst[9]=rlf(src,9);  dst[10]=rlf(src,10); dst[11]=rlf(src,11); \
  dst[12]=rlf(src,12); dst[13]=rlf(src,13); dst[14]=rlf(src,14); dst[15]=rlf(src,15); \
  dst[16]=rlf(src,16); dst[17]=rlf(src,17); dst[18]=rlf(src,18); dst[19]=rlf(src,19); }

__global__ __attribute__((amdgpu_waves_per_eu(1)))
__launch_bounds__(256, 1) void lstm_kernel(
    const float* __restrict__ xw, const float* __restrict__ wsF,
    const float* __restrict__ Whh0,
    const float* __restrict__ Wih1, const float* __restrict__ Whh1,
    const float* __restrict__ bih1, const float* __restrict__ bhh1,
    const float* __restrict__ Wv, const float* __restrict__ bv,
    float* __restrict__ out)
{
  __shared__ float xpbuf[2][2][128];   // [chain][slot][xpA(64) | xpB(64)]
  __shared__ float hb[2][20];
  int b = blockIdx.x;
  int tid = threadIdx.x;
  int wid = tid >> 6;
  int lane = tid & 63;
  int chain = wid >> 1;      // 0 = fwd chain b, 1 = rev chain B+b
  int role = wid & 1;        // 0 = producer (L1 + L2 input proj), 1 = consumer (L2)
  int jmod = lane % 20;
  int rA = lane, rB = 60 + jmod;
  int lf = (lane + 20) & 63;
  int lg = (lane + 40) & 63;
  int typ = lane / 20;
  float actB = (typ == 2) ? -2.f : -1.f;
  float actA = (typ == 2) ? 2.f : 1.f;
  float actC = (typ == 2) ? -1.f : 0.f;

  if (role == 0) {
    // ---------------- producer: L1 + xp2 projection ----------------
    float whA0[20], whB0[20], wiA1[20], wiB1[20];
    LOAD20(whA0, Whh0 + rA * 20); LOAD20(whB0, Whh0 + rB * 20);
    LOAD20(wiA1, Wih1 + rA * 20); LOAD20(wiB1, Wih1 + rB * 20);
    float bA1c = bih1[rA] + bhh1[rA];
    float bB1c = bih1[rB] + bhh1[rB];

    float sh1[20];
    float c1;
    const float* prow = xw + ((size_t)b * 256 + (chain ? 255 : 0)) * 80;
    int pstep = chain ? -80 : 80;
    float xwA0v = prow[rA], xwB0v = prow[rB];
    prow += pstep;
    float xwA1v = prow[rA], xwB1v = prow[rB];

    // L1 step 0 (input = mu projection, h=c=0)
    {
      float preA = wsF[WS_XWMU + rA];
      float preB = wsF[WS_XWMU + rB];
      float aA = fmaf(actA, __builtin_amdgcn_rcpf(1.f + __expf(actB * preA)), actC);
      float aB = sigm(preB);
      float gv = __shfl(aA, lg);
      c1 = aA * gv;
      float h1j = aB * tanh_fast(c1);
      READ_H(sh1, h1j);
    }

#pragma unroll 1
    for (int i = 1; i <= 258; ++i) {
      PIN20(whA0); PIN20(whB0); PIN20(wiA1); PIN20(wiB1);
      __syncthreads();
      if (i <= 257) {
        // xp2(i-1) = b1 + Wih1·h1(i-1)
        float xA0 = bA1c, xA1 = 0.f, xA2 = 0.f, xA3 = 0.f;
        float xB0 = bB1c, xB1 = 0.f, xB2 = 0.f, xB3 = 0.f;
#pragma unroll
        for (int k = 0; k < 5; ++k) {
          xA0 = fmaf(wiA1[4*k+0], sh1[4*k+0], xA0); xA1 = fmaf(wiA1[4*k+1], sh1[4*k+1], xA1);
          xA2 = fmaf(wiA1[4*k+2], sh1[4*k+2], xA2); xA3 = fmaf(wiA1[4*k+3], sh1[4*k+3], xA3);
          xB0 = fmaf(wiB1[4*k+0], sh1[4*k+0], xB0); xB1 = fmaf(wiB1[4*k+1], sh1[4*k+1], xB1);
          xB2 = fmaf(wiB1[4*k+2], sh1[4*k+2], xB2); xB3 = fmaf(wiB1[4*k+3], sh1[4*k+3], xB3);
        }
        int slot = (i - 1) & 1;
        xpbuf[chain][slot][lane]      = (xA0 + xA1) + (xA2 + xA3);
        xpbuf[chain][slot][64 + lane] = (xB0 + xB1) + (xB2 + xB3);
      }
      if (i <= 256) {
        // L1 step i: pre = xw(i) + Whh0·h1(i-1)
        float cxwA = xwA0v, cxwB = xwB0v;
        xwA0v = xwA1v; xwB0v = xwB1v;
        if (i <= 254) {
          prow += pstep;
          xwA1v = prow[rA]; xwB1v = prow[rB];
        }
        float a0 = cxwA, a1 = 0.f, a2 = 0.f, a3 = 0.f;
        float q0 = cxwB, q1 = 0.f, q2 = 0.f, q3 = 0.f;
#pragma unroll
        for (int k = 0; k < 5; ++k) {
          a0 = fmaf(whA0[4*k+0], sh1[4*k+0], a0); a1 = fmaf(whA0[4*k+1], sh1[4*k+1], a1);
          a2 = fmaf(whA0[4*k+2], sh1[4*k+2], a2); a3 = fmaf(whA0[4*k+3], sh1[4*k+3], a3);
          q0 = fmaf(whB0[4*k+0], sh1[4*k+0], q0); q1 = fmaf(whB0[4*k+1], sh1[4*k+1], q1);
          q2 = fmaf(whB0[4*k+2], sh1[4*k+2], q2); q3 = fmaf(whB0[4*k+3], sh1[4*k+3], q3);
        }
        float preA = (a0 + a1) + (a2 + a3);
        float preB = (q0 + q1) + (q2 + q3);
        float aA = fmaf(actA, __builtin_amdgcn_rcpf(1.f + __expf(actB * preA)), actC);
        float aB = sigm(preB);
        float fv = __shfl(aA, lf);
        float gv = __shfl(aA, lg);
        c1 = fmaf(fv, c1, aA * gv);
        float h1j = aB * tanh_fast(c1);
        READ_H(sh1, h1j);
      }
    }
  } else {
    // ---------------- consumer: L2 recurrence ----------------
    float whA1[20], whB1[20];
    LOAD20(whA1, Whh1 + rA * 20); LOAD20(whB1, Whh1 + rB * 20);
    float sh2[20];
#pragma unroll
    for (int k = 0; k < 20; ++k) sh2[k] = 0.f;
    float c2 = 0.f;

#pragma unroll 1
    for (int i = 1; i <= 258; ++i) {
      PIN20(whA1); PIN20(whB1);
      __syncthreads();
      if (i >= 2) {
        // L2 step (i-2): pre = xp2(i-2) + Whh1·h2(i-3); slot parity (i-2)&1 == i&1
        int slot = i & 1;
        float xpA = xpbuf[chain][slot][lane];
        float xpB = xpbuf[chain][slot][64 + lane];
        float u0 = 0.f, u1 = 0.f, u2 = 0.f, u3 = 0.f;
        float v0 = 0.f, v1 = 0.f, v2 = 0.f, v3 = 0.f;
#pragma unroll
        for (int k = 0; k < 5; ++k) {
          u0 = fmaf(whA1[4*k+0], sh2[4*k+0], u0); u1 = fmaf(whA1[4*k+1], sh2[4*k+1], u1);
          u2 = fmaf(whA1[4*k+2], sh2[4*k+2], u2); u3 = fmaf(whA1[4*k+3], sh2[4*k+3], u3);
          v0 = fmaf(whB1[4*k+0], sh2[4*k+0], v0); v1 = fmaf(whB1[4*k+1], sh2[4*k+1], v1);
          v2 = fmaf(whB1[4*k+2], sh2[4*k+2], v2); v3 = fmaf(whB1[4*k+3], sh2[4*k+3], v3);
        }
        float preA = ((u0 + u1) + (u2 + u3)) + xpA;
        float preB = ((v0 + v1) + (v2 + v3)) + xpB;
        float aA = fmaf(actA, __builtin_amdgcn_rcpf(1.f + __expf(actB * preA)), actC);
        float aB = sigm(preB);
        float fv = __shfl(aA, lf);
        float gv = __shfl(aA, lg);
        c2 = fmaf(fv, c2, aA * gv);
        float h2j = aB * tanh_fast(c2);
        if (lane < 20) hb[chain][lane] = h2j;
        READ_H(sh2, h2j);
      }
    }
  }

  __syncthreads();
  if (tid == 0) {
    float y = bv[0];
#pragma unroll
    for (int j = 0; j < 20; ++j) y = fmaf(Wv[j], hb[0][j], y);
#pragma unroll
    for (int j = 0; j < 20; ++j) y = fmaf(Wv[20 + j], hb[1][j], y);
    out[b] = y;
  }
}

extern "C" void kernel_launch(void* const* d_in, const int* in_sizes, int n_in,
                              void* d_out, int out_size, void* d_ws, size_t ws_size,
                              hipStream_t stream)
{
  const float* x    = (const float*)d_in[0];
  const float* W_N  = (const float*)d_in[1];
  const float* b_N  = (const float*)d_in[2];
  const float* W_up = (const float*)d_in[3];
  const float* b_up = (const float*)d_in[4];
  const float* mu   = (const float*)d_in[5];
  const float* Wih0 = (const float*)d_in[6];
  const float* Whh0 = (const float*)d_in[7];
  const float* bih0 = (const float*)d_in[8];
  const float* bhh0 = (const float*)d_in[9];
  const float* Wih1 = (const float*)d_in[10];
  const float* Whh1 = (const float*)d_in[11];
  const float* bih1 = (const float*)d_in[12];
  const float* bhh1 = (const float*)d_in[13];
  const float* Wv   = (const float*)d_in[14];
  const float* bvv  = (const float*)d_in[15];
  float* wsF = (float*)d_ws;
  float* xwp = wsF + WS_XW;
  float* outF = (float*)d_out;

  prep_cols_kernel<<<513, 256, 0, stream>>>(W_N, b_N, W_up, b_up, wsF);
  prep_mu_kernel<<<1, 128, 0, stream>>>(mu, Wih0, bih0, bhh0, wsF);
  xw_kernel<<<B_, 512, 0, stream>>>(x, Wih0, wsF, xwp);
  lstm_kernel<<<B_, 256, 0, stream>>>(xwp, wsF, Whh0, Wih1, Whh1,
                                      bih1, bhh1, Wv, bvv, outF);
}

// Round 6
// 145.646 us; speedup vs baseline: 3.4931x; 1.3218x over previous
//
#include <hip/hip_runtime.h>
#include <hip/hip_bf16.h>

#define B_ 256
#define S_ 512
#define F_ 256
#define L_ 20

// ws layout (floats):
//   [0,10240)      W_combT [512][20]
//   [10240,10260)  b_comb[20]
//   [10260,10340)  xw_mu[80]  = bih0+bhh0 + W_ih0·mu
//   [10340,10420)  bsum[80]   = bih0+bhh0
//   [16384, +256*256*80) xw0[b][f][80] = bsum + W_ih0·x_up[b][f][:]
#define WS_WCT 0
#define WS_BC  10240
#define WS_XWMU 10260
#define WS_BSUM 10340
#define WS_XW  16384

#define LOAD20(dst, ptr) { const float4* _p = (const float4*)(ptr); \
  float4 _a=_p[0], _b=_p[1], _c=_p[2], _d=_p[3], _e=_p[4]; \
  dst[0]=_a.x; dst[1]=_a.y; dst[2]=_a.z; dst[3]=_a.w; \
  dst[4]=_b.x; dst[5]=_b.y; dst[6]=_b.z; dst[7]=_b.w; \
  dst[8]=_c.x; dst[9]=_c.y; dst[10]=_c.z; dst[11]=_c.w; \
  dst[12]=_d.x; dst[13]=_d.y; dst[14]=_d.z; dst[15]=_d.w; \
  dst[16]=_e.x; dst[17]=_e.y; dst[18]=_e.z; dst[19]=_e.w; }

// Non-rematerializable weight load: compiler cannot re-execute volatile asm,
// so the loaded value MUST stay register-resident across the loop.
#define GISSUE4(dst, ptr) asm volatile("global_load_dwordx4 %0, %1, off" \
  : "=v"(dst) : "v"(ptr) : "memory")
#define GWAIT() { asm volatile("s_waitcnt vmcnt(0)" ::: "memory"); \
  __builtin_amdgcn_sched_barrier(0); }

// dot of a 5xfloat4 register row with a 20-float (SGPR/VGPR) array, 4-acc ILP
#define DOT20(res, W, S, init0, init1) { \
  float _a0 = (init0), _a1 = (init1), _a2 = 0.f, _a3 = 0.f; \
  _a0 = fmaf(W[0].x, S[0], _a0);  _a1 = fmaf(W[0].y, S[1], _a1); \
  _a2 = fmaf(W[0].z, S[2], _a2);  _a3 = fmaf(W[0].w, S[3], _a3); \
  _a0 = fmaf(W[1].x, S[4], _a0);  _a1 = fmaf(W[1].y, S[5], _a1); \
  _a2 = fmaf(W[1].z, S[6], _a2);  _a3 = fmaf(W[1].w, S[7], _a3); \
  _a0 = fmaf(W[2].x, S[8], _a0);  _a1 = fmaf(W[2].y, S[9], _a1); \
  _a2 = fmaf(W[2].z, S[10], _a2); _a3 = fmaf(W[2].w, S[11], _a3); \
  _a0 = fmaf(W[3].x, S[12], _a0); _a1 = fmaf(W[3].y, S[13], _a1); \
  _a2 = fmaf(W[3].z, S[14], _a2); _a3 = fmaf(W[3].w, S[15], _a3); \
  _a0 = fmaf(W[4].x, S[16], _a0); _a1 = fmaf(W[4].y, S[17], _a1); \
  _a2 = fmaf(W[4].z, S[18], _a2); _a3 = fmaf(W[4].w, S[19], _a3); \
  res = (_a0 + _a1) + (_a2 + _a3); }

#define GLOAD_ROW5(W, base) { \
  GISSUE4(W[0], (base) + 0);  GISSUE4(W[1], (base) + 4); \
  GISSUE4(W[2], (base) + 8);  GISSUE4(W[3], (base) + 12); \
  GISSUE4(W[4], (base) + 16); }

// ---------------- kernel 1a: W_combT columns + b_comb ----------------
__global__ __launch_bounds__(256) void prep_cols_kernel(
    const float* __restrict__ W_N, const float* __restrict__ b_N,
    const float* __restrict__ W_up, const float* __restrict__ b_up,
    float* __restrict__ wsF)
{
  __shared__ float wn[512];
  int s = blockIdx.x;                 // 0..511 -> column s; 512 -> b_comb
  int tid = threadIdx.x;
  bool isb = (s == 512);
  if (isb) {
    wn[tid] = b_N[tid];
    wn[tid + 256] = b_N[tid + 256];
  } else {
    wn[tid] = W_N[(size_t)tid * S_ + s];
    wn[tid + 256] = W_N[(size_t)(tid + 256) * S_ + s];
  }
  __syncthreads();
  int w = tid >> 6, lane = tid & 63;
#pragma unroll
  for (int li = 0; li < 5; ++li) {
    int l = w * 5 + li;
    const float* wu = W_up + (size_t)l * S_;
    float acc = 0.f;
#pragma unroll
    for (int j = 0; j < 8; ++j)
      acc = fmaf(wu[lane + 64 * j], wn[lane + 64 * j], acc);
    acc += __shfl_xor(acc, 1);  acc += __shfl_xor(acc, 2);
    acc += __shfl_xor(acc, 4);  acc += __shfl_xor(acc, 8);
    acc += __shfl_xor(acc, 16); acc += __shfl_xor(acc, 32);
    if (lane == 0) {
      if (isb) wsF[WS_BC + l] = acc + b_up[l];
      else     wsF[WS_WCT + s * 20 + l] = acc;
    }
  }
}

// ---------------- kernel 1b: xw_mu + bsum ----------------
__global__ __launch_bounds__(128) void prep_mu_kernel(
    const float* __restrict__ mu, const float* __restrict__ Wih0,
    const float* __restrict__ bih0, const float* __restrict__ bhh0,
    float* __restrict__ wsF)
{
  int tid = threadIdx.x;
  if (tid < 80) {
    float bs = bih0[tid] + bhh0[tid];
    wsF[WS_BSUM + tid] = bs;
    float acc = bs;
#pragma unroll
    for (int l = 0; l < 20; ++l) acc = fmaf(Wih0[tid * 20 + l], mu[l], acc);
    wsF[WS_XWMU + tid] = acc;
  }
}

// ---------------- kernel 2: x -> x_up -> xw0 (L1 gate pre-projections) ----------------
__global__ __launch_bounds__(512) void xw_kernel(
    const float* __restrict__ x, const float* __restrict__ Wih0,
    const float* __restrict__ wsF, float* __restrict__ xw)
{
  __shared__ __align__(16) float Wl[10240];      // W_combT, 40KB
  __shared__ __align__(16) float xu[F_ * L_];    // x_up tile, 20KB
  __shared__ __align__(16) float Wg[80 * 20];    // W_ih0, 6.4KB
  __shared__ float bsumL[80];
  __shared__ float bcL[20];
  int b = blockIdx.x;
  int tid = threadIdx.x;
  {
    const float4* srcw = (const float4*)(wsF + WS_WCT);
    float4* dstw = (float4*)Wl;
    for (int i = tid; i < 2560; i += 512) dstw[i] = srcw[i];
    const float4* srcg = (const float4*)Wih0;
    float4* dstg = (float4*)Wg;
    for (int i = tid; i < 400; i += 512) dstg[i] = srcg[i];
    if (tid < 80) bsumL[tid] = wsF[WS_BSUM + tid];
    if (tid < 20) bcL[tid] = wsF[WS_BC + tid];
  }
  __syncthreads();
  int f = tid & 255;
  int p = tid >> 8;                 // s-parity split
  float acc[20];
#pragma unroll
  for (int l = 0; l < 20; ++l) acc[l] = 0.f;
  const float* xb = x + (size_t)b * S_ * F_ + f;
#pragma unroll 1
  for (int sg = 0; sg < S_; sg += 16) {
    float xv[8];
#pragma unroll
    for (int u = 0; u < 8; ++u) xv[u] = xb[(size_t)(sg + p + 2 * u) * F_];
#pragma unroll
    for (int u = 0; u < 8; ++u) {
      int s = sg + p + 2 * u;
      const float4* wp = (const float4*)(Wl + s * 20);
      float4 w0 = wp[0], w1 = wp[1], w2 = wp[2], w3 = wp[3], w4 = wp[4];
      acc[0] = fmaf(w0.x, xv[u], acc[0]);  acc[1] = fmaf(w0.y, xv[u], acc[1]);
      acc[2] = fmaf(w0.z, xv[u], acc[2]);  acc[3] = fmaf(w0.w, xv[u], acc[3]);
      acc[4] = fmaf(w1.x, xv[u], acc[4]);  acc[5] = fmaf(w1.y, xv[u], acc[5]);
      acc[6] = fmaf(w1.z, xv[u], acc[6]);  acc[7] = fmaf(w1.w, xv[u], acc[7]);
      acc[8] = fmaf(w2.x, xv[u], acc[8]);  acc[9] = fmaf(w2.y, xv[u], acc[9]);
      acc[10] = fmaf(w2.z, xv[u], acc[10]); acc[11] = fmaf(w2.w, xv[u], acc[11]);
      acc[12] = fmaf(w3.x, xv[u], acc[12]); acc[13] = fmaf(w3.y, xv[u], acc[13]);
      acc[14] = fmaf(w3.z, xv[u], acc[14]); acc[15] = fmaf(w3.w, xv[u], acc[15]);
      acc[16] = fmaf(w4.x, xv[u], acc[16]); acc[17] = fmaf(w4.y, xv[u], acc[17]);
      acc[18] = fmaf(w4.z, xv[u], acc[18]); acc[19] = fmaf(w4.w, xv[u], acc[19]);
    }
  }
  if (p == 1) {
#pragma unroll
    for (int l = 0; l < 20; ++l) xu[f * 20 + l] = acc[l];
  }
  __syncthreads();
  if (p == 0) {
#pragma unroll
    for (int l = 0; l < 20; ++l) xu[f * 20 + l] = acc[l] + xu[f * 20 + l] + bcL[l];
  }
  __syncthreads();
  // projection: thread (f2, half) computes gates [half*40, half*40+40)
  int f2 = tid >> 1, half = tid & 1;
  float xr[20];
  LOAD20(xr, xu + f2 * 20);
  float* ob = xw + ((size_t)b * 256 + f2) * 80 + half * 40;
  const float* wgbase = Wg + half * 40 * 20;
  const float* bsb = bsumL + half * 40;
#pragma unroll 2
  for (int g = 0; g < 40; ++g) {
    const float4* wp = (const float4*)(wgbase + g * 20);
    float4 w0 = wp[0], w1 = wp[1], w2 = wp[2], w3 = wp[3], w4 = wp[4];
    float a0 = bsb[g], a1 = 0.f, a2 = 0.f, a3 = 0.f;
    a0 = fmaf(w0.x, xr[0], a0);  a1 = fmaf(w0.y, xr[1], a1);
    a2 = fmaf(w0.z, xr[2], a2);  a3 = fmaf(w0.w, xr[3], a3);
    a0 = fmaf(w1.x, xr[4], a0);  a1 = fmaf(w1.y, xr[5], a1);
    a2 = fmaf(w1.z, xr[6], a2);  a3 = fmaf(w1.w, xr[7], a3);
    a0 = fmaf(w2.x, xr[8], a0);  a1 = fmaf(w2.y, xr[9], a1);
    a2 = fmaf(w2.z, xr[10], a2); a3 = fmaf(w2.w, xr[11], a3);
    a0 = fmaf(w3.x, xr[12], a0); a1 = fmaf(w3.y, xr[13], a1);
    a2 = fmaf(w3.z, xr[14], a2); a3 = fmaf(w3.w, xr[15], a3);
    a0 = fmaf(w4.x, xr[16], a0); a1 = fmaf(w4.y, xr[17], a1);
    a2 = fmaf(w4.z, xr[18], a2); a3 = fmaf(w4.w, xr[19], a3);
    ob[g] = (a0 + a1) + (a2 + a3);
  }
}

// ---------------- kernel 3: 3-wave-per-chain pipelined LSTM ----------
// Block = 384 threads = 6 waves = 2 chains x 3 roles:
//   role0: L1 recurrence (Whh0 rows A=lane, B=60+lane%20), writes h1 -> LDS
//   role1: L2 input projection xp2 = b1 + Wih1*h1 (reads h1 from LDS), writes xp -> LDS
//   role2: L2 recurrence (Whh1 rows + xp from LDS)
// Pipeline: h1(t) [iter t] -> xp2(t) [iter t+1] -> h2(t) [iter t+2]; parity LDS slots,
// one __syncthreads per iteration, identical barrier counts in all roles.
__device__ __forceinline__ float rlf(float v, int k) {
  return __int_as_float(__builtin_amdgcn_readlane(__float_as_int(v), k));
}
__device__ __forceinline__ float sigm(float x) {
  return __builtin_amdgcn_rcpf(1.f + __expf(-x));
}
__device__ __forceinline__ float tanh_fast(float x) {
  return fmaf(2.f, __builtin_amdgcn_rcpf(1.f + __expf(-2.f * x)), -1.f);
}

#define READ_H(dst, src) { \
  dst[0]=rlf(src,0);  dst[1]=rlf(src,1);  dst[2]=rlf(src,2);  dst[3]=rlf(src,3); \
  dst[4]=rlf(src,4);  dst[5]=rlf(src,5);  dst[6]=rlf(src,6);  dst[7]=rlf(src,7); \
  dst[8]=rlf(src,8);  dst[9]=rlf(src,9);  dst[10]=rlf(src,10); dst[11]=rlf(src,11); \
  dst[12]=rlf(src,12); dst[13]=rlf(src,13); dst[14]=rlf(src,14); dst[15]=rlf(src,15); \
  dst[16]=rlf(src,16); dst[17]=rlf(src,17); dst[18]=rlf(src,18); dst[19]=rlf(src,19); }

__global__ __launch_bounds__(384, 1) void lstm_kernel(
    const float* __restrict__ xw, const float* __restrict__ wsF,
    const float* __restrict__ Whh0,
    const float* __restrict__ Wih1, const float* __restrict__ Whh1,
    const float* __restrict__ bih1, const float* __restrict__ bhh1,
    const float* __restrict__ Wv, const float* __restrict__ bv,
    float* __restrict__ out)
{
  __shared__ __align__(16) float h1buf[2][2][20];   // [chain][slot][unit]
  __shared__ __align__(16) float xpbuf[2][2][128];  // [chain][slot][xpA(64)|xpB(64)]
  __shared__ float hb[2][20];
  int b = blockIdx.x;
  int tid = threadIdx.x;
  int wid = tid >> 6;
  int lane = tid & 63;
  int chain = wid / 3;       // 0 = fwd chain b, 1 = rev chain B+b
  int role = wid % 3;
  int jmod = lane % 20;
  int rA = lane, rB = 60 + jmod;
  int lf = (lane + 20) & 63;
  int lg = (lane + 40) & 63;
  int typ = lane / 20;
  float actB = (typ == 2) ? -2.f : -1.f;
  float actA = (typ == 2) ? 2.f : 1.f;
  float actC = (typ == 2) ? -1.f : 0.f;

  if (role == 0) {
    // ---------------- role0: L1 recurrence ----------------
    float4 wA[5], wB[5];
    GLOAD_ROW5(wA, Whh0 + rA * 20);
    GLOAD_ROW5(wB, Whh0 + rB * 20);
    GWAIT();
    const float* prow = xw + ((size_t)b * 256 + (chain ? 255 : 0)) * 80;
    int pstep = chain ? -80 : 80;
    float xwA0v = prow[rA], xwB0v = prow[rB];
    prow += pstep;
    float xwA1v = prow[rA], xwB1v = prow[rB];

    float sh1[20];
    float c1;
    {   // L1 step 0 (input = mu projection, h=c=0)
      float preA = wsF[WS_XWMU + rA];
      float preB = wsF[WS_XWMU + rB];
      float aA = fmaf(actA, __builtin_amdgcn_rcpf(1.f + __expf(actB * preA)), actC);
      float aB = sigm(preB);
      float gv = __shfl(aA, lg);
      c1 = aA * gv;
      float h1j = aB * tanh_fast(c1);
      if (lane < 20) h1buf[chain][0][lane] = h1j;
      READ_H(sh1, h1j);
    }
#pragma unroll 1
    for (int i = 1; i <= 258; ++i) {
      __syncthreads();
      if (i <= 256) {
        float cxwA = xwA0v, cxwB = xwB0v;
        xwA0v = xwA1v; xwB0v = xwB1v;
        if (i <= 254) { prow += pstep; xwA1v = prow[rA]; xwB1v = prow[rB]; }
        float preA, preB;
        DOT20(preA, wA, sh1, cxwA, 0.f);
        DOT20(preB, wB, sh1, cxwB, 0.f);
        float aA = fmaf(actA, __builtin_amdgcn_rcpf(1.f + __expf(actB * preA)), actC);
        float aB = sigm(preB);
        float fv = __shfl(aA, lf);
        float gv = __shfl(aA, lg);
        c1 = fmaf(fv, c1, aA * gv);
        float h1j = aB * tanh_fast(c1);
        if (lane < 20) h1buf[chain][i & 1][lane] = h1j;
        READ_H(sh1, h1j);
      }
    }
  } else if (role == 1) {
    // ---------------- role1: xp2 projection ----------------
    float4 iA[5], iB[5];
    GLOAD_ROW5(iA, Wih1 + rA * 20);
    GLOAD_ROW5(iB, Wih1 + rB * 20);
    GWAIT();
    float bA1c = bih1[rA] + bhh1[rA];
    float bB1c = bih1[rB] + bhh1[rB];
#pragma unroll 1
    for (int i = 1; i <= 258; ++i) {
      __syncthreads();
      if (i <= 257) {
        int slot = (i - 1) & 1;
        float hv[20];
        LOAD20(hv, &h1buf[chain][slot][0]);
        float xpA, xpB;
        DOT20(xpA, iA, hv, bA1c, 0.f);
        DOT20(xpB, iB, hv, bB1c, 0.f);
        xpbuf[chain][slot][lane] = xpA;
        xpbuf[chain][slot][64 + lane] = xpB;
      }
    }
  } else {
    // ---------------- role2: L2 recurrence ----------------
    float4 hA[5], hBq[5];
    GLOAD_ROW5(hA, Whh1 + rA * 20);
    GLOAD_ROW5(hBq, Whh1 + rB * 20);
    GWAIT();
    float sh2[20];
#pragma unroll
    for (int k = 0; k < 20; ++k) sh2[k] = 0.f;
    float c2 = 0.f;
    float h2last = 0.f;
#pragma unroll 1
    for (int i = 1; i <= 258; ++i) {
      __syncthreads();
      if (i >= 2) {
        int slot = i & 1;                       // = (i-2)&1
        float xpA = xpbuf[chain][slot][lane];
        float xpB = xpbuf[chain][slot][64 + lane];
        float preA, preB;
        DOT20(preA, hA, sh2, xpA, 0.f);
        DOT20(preB, hBq, sh2, xpB, 0.f);
        float aA = fmaf(actA, __builtin_amdgcn_rcpf(1.f + __expf(actB * preA)), actC);
        float aB = sigm(preB);
        float fv = __shfl(aA, lf);
        float gv = __shfl(aA, lg);
        c2 = fmaf(fv, c2, aA * gv);
        float h2j = aB * tanh_fast(c2);
        h2last = h2j;
        READ_H(sh2, h2j);
      }
    }
    if (lane < 20) hb[chain][lane] = h2last;
  }

  __syncthreads();
  if (tid == 0) {
    float y = bv[0];
#pragma unroll
    for (int j = 0; j < 20; ++j) y = fmaf(Wv[j], hb[0][j], y);
#pragma unroll
    for (int j = 0; j < 20; ++j) y = fmaf(Wv[20 + j], hb[1][j], y);
    out[b] = y;
  }
}

extern "C" void kernel_launch(void* const* d_in, const int* in_sizes, int n_in,
                              void* d_out, int out_size, void* d_ws, size_t ws_size,
                              hipStream_t stream)
{
  const float* x    = (const float*)d_in[0];
  const float* W_N  = (const float*)d_in[1];
  const float* b_N  = (const float*)d_in[2];
  const float* W_up = (const float*)d_in[3];
  const float* b_up = (const float*)d_in[4];
  const float* mu   = (const float*)d_in[5];
  const float* Wih0 = (const float*)d_in[6];
  const float* Whh0 = (const float*)d_in[7];
  const float* bih0 = (const float*)d_in[8];
  const float* bhh0 = (const float*)d_in[9];
  const float* Wih1 = (const float*)d_in[10];
  const float* Whh1 = (const float*)d_in[11];
  const float* bih1 = (const float*)d_in[12];
  const float* bhh1 = (const float*)d_in[13];
  const float* Wv   = (const float*)d_in[14];
  const float* bvv  = (const float*)d_in[15];
  float* wsF = (float*)d_ws;
  float* xwp = wsF + WS_XW;
  float* outF = (float*)d_out;

  prep_cols_kernel<<<513, 256, 0, stream>>>(W_N, b_N, W_up, b_up, wsF);
  prep_mu_kernel<<<1, 128, 0, stream>>>(mu, Wih0, bih0, bhh0, wsF);
  xw_kernel<<<B_, 512, 0, stream>>>(x, Wih0, wsF, xwp);
  lstm_kernel<<<B_, 384, 0, stream>>>(xwp, wsF, Whh0, Wih1, Whh1,
                                      bih1, bhh1, Wv, bvv, outF);
}

// Round 7
// 145.566 us; speedup vs baseline: 3.4950x; 1.0005x over previous
//
#include <hip/hip_runtime.h>
#include <hip/hip_bf16.h>

#define B_ 256
#define S_ 512
#define F_ 256
#define L_ 20

// ws layout (floats):
//   [0,10240)      W_combT [512][20]
//   [10240,10260)  b_comb[20]
//   [10260,10340)  xw_mu[80]  = bih0+bhh0 + W_ih0·mu
//   [10340,10420)  bsum[80]   = bih0+bhh0
//   [16384, +256*256*80) xw0[b][f][80] = bsum + W_ih0·x_up[b][f][:]
#define WS_WCT 0
#define WS_BC  10240
#define WS_XWMU 10260
#define WS_BSUM 10340
#define WS_XW  16384

#define LOAD20(dst, ptr) { const float4* _p = (const float4*)(ptr); \
  float4 _a=_p[0], _b=_p[1], _c=_p[2], _d=_p[3], _e=_p[4]; \
  dst[0]=_a.x; dst[1]=_a.y; dst[2]=_a.z; dst[3]=_a.w; \
  dst[4]=_b.x; dst[5]=_b.y; dst[6]=_b.z; dst[7]=_b.w; \
  dst[8]=_c.x; dst[9]=_c.y; dst[10]=_c.z; dst[11]=_c.w; \
  dst[12]=_d.x; dst[13]=_d.y; dst[14]=_d.z; dst[15]=_d.w; \
  dst[16]=_e.x; dst[17]=_e.y; dst[18]=_e.z; dst[19]=_e.w; }

// Non-rematerializable weight load: compiler cannot re-execute volatile asm,
// so the loaded value MUST stay register-resident across the loop.
#define GISSUE4(dst, ptr) asm volatile("global_load_dwordx4 %0, %1, off" \
  : "=v"(dst) : "v"(ptr) : "memory")
#define GWAIT() { asm volatile("s_waitcnt vmcnt(0)" ::: "memory"); \
  __builtin_amdgcn_sched_barrier(0); }

// Raw barrier that does NOT drain vmcnt: flush LDS writes (lgkmcnt) only.
// Bracketed by compiler memory fences so LDS ops can't cross it.
#define BARSYNC() { asm volatile("s_waitcnt lgkmcnt(0)" ::: "memory"); \
  __builtin_amdgcn_s_barrier(); \
  asm volatile("" ::: "memory"); }

// dot of a 5xfloat4 register row with a 20-float (SGPR/VGPR) array, 4-acc ILP
#define DOT20(res, W, S, init0, init1) { \
  float _a0 = (init0), _a1 = (init1), _a2 = 0.f, _a3 = 0.f; \
  _a0 = fmaf(W[0].x, S[0], _a0);  _a1 = fmaf(W[0].y, S[1], _a1); \
  _a2 = fmaf(W[0].z, S[2], _a2);  _a3 = fmaf(W[0].w, S[3], _a3); \
  _a0 = fmaf(W[1].x, S[4], _a0);  _a1 = fmaf(W[1].y, S[5], _a1); \
  _a2 = fmaf(W[1].z, S[6], _a2);  _a3 = fmaf(W[1].w, S[7], _a3); \
  _a0 = fmaf(W[2].x, S[8], _a0);  _a1 = fmaf(W[2].y, S[9], _a1); \
  _a2 = fmaf(W[2].z, S[10], _a2); _a3 = fmaf(W[2].w, S[11], _a3); \
  _a0 = fmaf(W[3].x, S[12], _a0); _a1 = fmaf(W[3].y, S[13], _a1); \
  _a2 = fmaf(W[3].z, S[14], _a2); _a3 = fmaf(W[3].w, S[15], _a3); \
  _a0 = fmaf(W[4].x, S[16], _a0); _a1 = fmaf(W[4].y, S[17], _a1); \
  _a2 = fmaf(W[4].z, S[18], _a2); _a3 = fmaf(W[4].w, S[19], _a3); \
  res = (_a0 + _a1) + (_a2 + _a3); }

#define GLOAD_ROW5(W, base) { \
  GISSUE4(W[0], (base) + 0);  GISSUE4(W[1], (base) + 4); \
  GISSUE4(W[2], (base) + 8);  GISSUE4(W[3], (base) + 12); \
  GISSUE4(W[4], (base) + 16); }

// ---------------- kernel 1a: W_combT columns + b_comb ----------------
__global__ __launch_bounds__(256) void prep_cols_kernel(
    const float* __restrict__ W_N, const float* __restrict__ b_N,
    const float* __restrict__ W_up, const float* __restrict__ b_up,
    float* __restrict__ wsF)
{
  __shared__ float wn[512];
  int s = blockIdx.x;                 // 0..511 -> column s; 512 -> b_comb
  int tid = threadIdx.x;
  bool isb = (s == 512);
  if (isb) {
    wn[tid] = b_N[tid];
    wn[tid + 256] = b_N[tid + 256];
  } else {
    wn[tid] = W_N[(size_t)tid * S_ + s];
    wn[tid + 256] = W_N[(size_t)(tid + 256) * S_ + s];
  }
  __syncthreads();
  int w = tid >> 6, lane = tid & 63;
#pragma unroll
  for (int li = 0; li < 5; ++li) {
    int l = w * 5 + li;
    const float* wu = W_up + (size_t)l * S_;
    float acc = 0.f;
#pragma unroll
    for (int j = 0; j < 8; ++j)
      acc = fmaf(wu[lane + 64 * j], wn[lane + 64 * j], acc);
    acc += __shfl_xor(acc, 1);  acc += __shfl_xor(acc, 2);
    acc += __shfl_xor(acc, 4);  acc += __shfl_xor(acc, 8);
    acc += __shfl_xor(acc, 16); acc += __shfl_xor(acc, 32);
    if (lane == 0) {
      if (isb) wsF[WS_BC + l] = acc + b_up[l];
      else     wsF[WS_WCT + s * 20 + l] = acc;
    }
  }
}

// ---------------- kernel 1b: xw_mu + bsum ----------------
__global__ __launch_bounds__(128) void prep_mu_kernel(
    const float* __restrict__ mu, const float* __restrict__ Wih0,
    const float* __restrict__ bih0, const float* __restrict__ bhh0,
    float* __restrict__ wsF)
{
  int tid = threadIdx.x;
  if (tid < 80) {
    float bs = bih0[tid] + bhh0[tid];
    wsF[WS_BSUM + tid] = bs;
    float acc = bs;
#pragma unroll
    for (int l = 0; l < 20; ++l) acc = fmaf(Wih0[tid * 20 + l], mu[l], acc);
    wsF[WS_XWMU + tid] = acc;
  }
}

// ---------------- kernel 2: x -> x_up -> xw0 (L1 gate pre-projections) ----------------
__global__ __launch_bounds__(512) void xw_kernel(
    const float* __restrict__ x, const float* __restrict__ Wih0,
    const float* __restrict__ wsF, float* __restrict__ xw)
{
  __shared__ __align__(16) float Wl[10240];      // W_combT, 40KB
  __shared__ __align__(16) float xu[F_ * L_];    // x_up tile, 20KB
  __shared__ __align__(16) float Wg[80 * 20];    // W_ih0, 6.4KB
  __shared__ float bsumL[80];
  __shared__ float bcL[20];
  int b = blockIdx.x;
  int tid = threadIdx.x;
  {
    const float4* srcw = (const float4*)(wsF + WS_WCT);
    float4* dstw = (float4*)Wl;
    for (int i = tid; i < 2560; i += 512) dstw[i] = srcw[i];
    const float4* srcg = (const float4*)Wih0;
    float4* dstg = (float4*)Wg;
    for (int i = tid; i < 400; i += 512) dstg[i] = srcg[i];
    if (tid < 80) bsumL[tid] = wsF[WS_BSUM + tid];
    if (tid < 20) bcL[tid] = wsF[WS_BC + tid];
  }
  __syncthreads();
  int f = tid & 255;
  int p = tid >> 8;                 // s-parity split
  float acc[20];
#pragma unroll
  for (int l = 0; l < 20; ++l) acc[l] = 0.f;
  const float* xb = x + (size_t)b * S_ * F_ + f;
#pragma unroll 1
  for (int sg = 0; sg < S_; sg += 16) {
    float xv[8];
#pragma unroll
    for (int u = 0; u < 8; ++u) xv[u] = xb[(size_t)(sg + p + 2 * u) * F_];
#pragma unroll
    for (int u = 0; u < 8; ++u) {
      int s = sg + p + 2 * u;
      const float4* wp = (const float4*)(Wl + s * 20);
      float4 w0 = wp[0], w1 = wp[1], w2 = wp[2], w3 = wp[3], w4 = wp[4];
      acc[0] = fmaf(w0.x, xv[u], acc[0]);  acc[1] = fmaf(w0.y, xv[u], acc[1]);
      acc[2] = fmaf(w0.z, xv[u], acc[2]);  acc[3] = fmaf(w0.w, xv[u], acc[3]);
      acc[4] = fmaf(w1.x, xv[u], acc[4]);  acc[5] = fmaf(w1.y, xv[u], acc[5]);
      acc[6] = fmaf(w1.z, xv[u], acc[6]);  acc[7] = fmaf(w1.w, xv[u], acc[7]);
      acc[8] = fmaf(w2.x, xv[u], acc[8]);  acc[9] = fmaf(w2.y, xv[u], acc[9]);
      acc[10] = fmaf(w2.z, xv[u], acc[10]); acc[11] = fmaf(w2.w, xv[u], acc[11]);
      acc[12] = fmaf(w3.x, xv[u], acc[12]); acc[13] = fmaf(w3.y, xv[u], acc[13]);
      acc[14] = fmaf(w3.z, xv[u], acc[14]); acc[15] = fmaf(w3.w, xv[u], acc[15]);
      acc[16] = fmaf(w4.x, xv[u], acc[16]); acc[17] = fmaf(w4.y, xv[u], acc[17]);
      acc[18] = fmaf(w4.z, xv[u], acc[18]); acc[19] = fmaf(w4.w, xv[u], acc[19]);
    }
  }
  if (p == 1) {
#pragma unroll
    for (int l = 0; l < 20; ++l) xu[f * 20 + l] = acc[l];
  }
  __syncthreads();
  if (p == 0) {
#pragma unroll
    for (int l = 0; l < 20; ++l) xu[f * 20 + l] = acc[l] + xu[f * 20 + l] + bcL[l];
  }
  __syncthreads();
  // projection: thread (f2, half) computes gates [half*40, half*40+40)
  int f2 = tid >> 1, half = tid & 1;
  float xr[20];
  LOAD20(xr, xu + f2 * 20);
  float* ob = xw + ((size_t)b * 256 + f2) * 80 + half * 40;
  const float* wgbase = Wg + half * 40 * 20;
  const float* bsb = bsumL + half * 40;
#pragma unroll 2
  for (int g = 0; g < 40; ++g) {
    const float4* wp = (const float4*)(wgbase + g * 20);
    float4 w0 = wp[0], w1 = wp[1], w2 = wp[2], w3 = wp[3], w4 = wp[4];
    float a0 = bsb[g], a1 = 0.f, a2 = 0.f, a3 = 0.f;
    a0 = fmaf(w0.x, xr[0], a0);  a1 = fmaf(w0.y, xr[1], a1);
    a2 = fmaf(w0.z, xr[2], a2);  a3 = fmaf(w0.w, xr[3], a3);
    a0 = fmaf(w1.x, xr[4], a0);  a1 = fmaf(w1.y, xr[5], a1);
    a2 = fmaf(w1.z, xr[6], a2);  a3 = fmaf(w1.w, xr[7], a3);
    a0 = fmaf(w2.x, xr[8], a0);  a1 = fmaf(w2.y, xr[9], a1);
    a2 = fmaf(w2.z, xr[10], a2); a3 = fmaf(w2.w, xr[11], a3);
    a0 = fmaf(w3.x, xr[12], a0); a1 = fmaf(w3.y, xr[13], a1);
    a2 = fmaf(w3.z, xr[14], a2); a3 = fmaf(w3.w, xr[15], a3);
    a0 = fmaf(w4.x, xr[16], a0); a1 = fmaf(w4.y, xr[17], a1);
    a2 = fmaf(w4.z, xr[18], a2); a3 = fmaf(w4.w, xr[19], a3);
    ob[g] = (a0 + a1) + (a2 + a3);
  }
}

// ---------------- kernel 3: 3-wave-per-chain pipelined LSTM ----------
// Roles as in round 6; barriers are now raw s_barrier + lgkmcnt-only flush
// (vmcnt NOT drained -> role0's xw prefetch survives across steps), and
// role0 runs a depth-4 static register prefetch ring (4x unrolled loop).
__device__ __forceinline__ float rlf(float v, int k) {
  return __int_as_float(__builtin_amdgcn_readlane(__float_as_int(v), k));
}
__device__ __forceinline__ float sigm(float x) {
  return __builtin_amdgcn_rcpf(1.f + __expf(-x));
}
__device__ __forceinline__ float tanh_fast(float x) {
  return fmaf(2.f, __builtin_amdgcn_rcpf(1.f + __expf(-2.f * x)), -1.f);
}

#define READ_H(dst, src) { \
  dst[0]=rlf(src,0);  dst[1]=rlf(src,1);  dst[2]=rlf(src,2);  dst[3]=rlf(src,3); \
  dst[4]=rlf(src,4);  dst[5]=rlf(src,5);  dst[6]=rlf(src,6);  dst[7]=rlf(src,7); \
  dst[8]=rlf(src,8);  dst[9]=rlf(src,9);  dst[10]=rlf(src,10); dst[11]=rlf(src,11); \
  dst[12]=rlf(src,12); dst[13]=rlf(src,13); dst[14]=rlf(src,14); dst[15]=rlf(src,15); \
  dst[16]=rlf(src,16); dst[17]=rlf(src,17); dst[18]=rlf(src,18); dst[19]=rlf(src,19); }

// one L1 step: consume prefetch slot (PA,PB) for step STEP, reload it for STEP+4
#define L1_SUBSTEP(PA, PB, STEP) { \
  BARSYNC(); \
  float preA, preB; \
  DOT20(preA, wA, sh1, PA, 0.f); \
  DOT20(preB, wB, sh1, PB, 0.f); \
  PA = prow[rA]; PB = prow[rB]; \
  prow += ((STEP) <= 251) ? pstep : 0; \
  float aA = fmaf(actA, __builtin_amdgcn_rcpf(1.f + __expf(actB * preA)), actC); \
  float aB = sigm(preB); \
  float fv = __shfl(aA, lf); \
  float gv = __shfl(aA, lg); \
  c1 = fmaf(fv, c1, aA * gv); \
  float h1j = aB * tanh_fast(c1); \
  if (lane < 20) h1buf[chain][(STEP) & 1][lane] = h1j; \
  READ_H(sh1, h1j); }

__global__ __launch_bounds__(384, 1) void lstm_kernel(
    const float* __restrict__ xw, const float* __restrict__ wsF,
    const float* __restrict__ Whh0,
    const float* __restrict__ Wih1, const float* __restrict__ Whh1,
    const float* __restrict__ bih1, const float* __restrict__ bhh1,
    const float* __restrict__ Wv, const float* __restrict__ bv,
    float* __restrict__ out)
{
  __shared__ __align__(16) float h1buf[2][2][20];   // [chain][slot][unit]
  __shared__ __align__(16) float xpbuf[2][2][128];  // [chain][slot][xpA(64)|xpB(64)]
  __shared__ float hb[2][20];
  int b = blockIdx.x;
  int tid = threadIdx.x;
  int wid = tid >> 6;
  int lane = tid & 63;
  int chain = wid / 3;       // 0 = fwd chain b, 1 = rev chain B+b
  int role = wid % 3;
  int jmod = lane % 20;
  int rA = lane, rB = 60 + jmod;
  int lf = (lane + 20) & 63;
  int lg = (lane + 40) & 63;
  int typ = lane / 20;
  float actB = (typ == 2) ? -2.f : -1.f;
  float actA = (typ == 2) ? 2.f : 1.f;
  float actC = (typ == 2) ? -1.f : 0.f;

  if (role == 0) {
    // ---------------- role0: L1 recurrence, depth-4 xw prefetch ring ----------------
    float4 wA[5], wB[5];
    GLOAD_ROW5(wA, Whh0 + rA * 20);
    GLOAD_ROW5(wB, Whh0 + rB * 20);
    GWAIT();
    const float* prow = xw + ((size_t)b * 256 + (chain ? 255 : 0)) * 80;
    int pstep = chain ? -80 : 80;
    // ring slots for steps 1..4
    float pA0 = prow[rA], pB0 = prow[rB]; prow += pstep;
    float pA1 = prow[rA], pB1 = prow[rB]; prow += pstep;
    float pA2 = prow[rA], pB2 = prow[rB]; prow += pstep;
    float pA3 = prow[rA], pB3 = prow[rB]; prow += pstep;  // prow -> row for step 5

    float sh1[20];
    float c1;
    {   // L1 step 0 (input = mu projection, h=c=0)
      float preA = wsF[WS_XWMU + rA];
      float preB = wsF[WS_XWMU + rB];
      float aA = fmaf(actA, __builtin_amdgcn_rcpf(1.f + __expf(actB * preA)), actC);
      float aB = sigm(preB);
      float gv = __shfl(aA, lg);
      c1 = aA * gv;
      float h1j = aB * tanh_fast(c1);
      if (lane < 20) h1buf[chain][0][lane] = h1j;
      READ_H(sh1, h1j);
    }
#pragma unroll 1
    for (int i = 1; i <= 253; i += 4) {
      L1_SUBSTEP(pA0, pB0, i);
      L1_SUBSTEP(pA1, pB1, i + 1);
      L1_SUBSTEP(pA2, pB2, i + 2);
      L1_SUBSTEP(pA3, pB3, i + 3);
    }
    BARSYNC();   // step 257 slot
    BARSYNC();   // step 258 slot
  } else if (role == 1) {
    // ---------------- role1: xp2 projection ----------------
    float4 iA[5], iB[5];
    GLOAD_ROW5(iA, Wih1 + rA * 20);
    GLOAD_ROW5(iB, Wih1 + rB * 20);
    GWAIT();
    float bA1c = bih1[rA] + bhh1[rA];
    float bB1c = bih1[rB] + bhh1[rB];
#pragma unroll 1
    for (int i = 1; i <= 258; ++i) {
      BARSYNC();
      if (i <= 257) {
        int slot = (i - 1) & 1;
        float hv[20];
        LOAD20(hv, &h1buf[chain][slot][0]);
        float xpA, xpB;
        DOT20(xpA, iA, hv, bA1c, 0.f);
        DOT20(xpB, iB, hv, bB1c, 0.f);
        xpbuf[chain][slot][lane] = xpA;
        xpbuf[chain][slot][64 + lane] = xpB;
      }
    }
  } else {
    // ---------------- role2: L2 recurrence ----------------
    float4 hA[5], hBq[5];
    GLOAD_ROW5(hA, Whh1 + rA * 20);
    GLOAD_ROW5(hBq, Whh1 + rB * 20);
    GWAIT();
    float sh2[20];
#pragma unroll
    for (int k = 0; k < 20; ++k) sh2[k] = 0.f;
    float c2 = 0.f;
    float h2last = 0.f;
#pragma unroll 1
    for (int i = 1; i <= 258; ++i) {
      BARSYNC();
      if (i >= 2) {
        int slot = i & 1;                       // = (i-2)&1
        float xpA = xpbuf[chain][slot][lane];
        float xpB = xpbuf[chain][slot][64 + lane];
        float preA, preB;
        DOT20(preA, hA, sh2, xpA, 0.f);
        DOT20(preB, hBq, sh2, xpB, 0.f);
        float aA = fmaf(actA, __builtin_amdgcn_rcpf(1.f + __expf(actB * preA)), actC);
        float aB = sigm(preB);
        float fv = __shfl(aA, lf);
        float gv = __shfl(aA, lg);
        c2 = fmaf(fv, c2, aA * gv);
        float h2j = aB * tanh_fast(c2);
        h2last = h2j;
        READ_H(sh2, h2j);
      }
    }
    if (lane < 20) hb[chain][lane] = h2last;
  }

  __syncthreads();
  if (tid == 0) {
    float y = bv[0];
#pragma unroll
    for (int j = 0; j < 20; ++j) y = fmaf(Wv[j], hb[0][j], y);
#pragma unroll
    for (int j = 0; j < 20; ++j) y = fmaf(Wv[20 + j], hb[1][j], y);
    out[b] = y;
  }
}

extern "C" void kernel_launch(void* const* d_in, const int* in_sizes, int n_in,
                              void* d_out, int out_size, void* d_ws, size_t ws_size,
                              hipStream_t stream)
{
  const float* x    = (const float*)d_in[0];
  const float* W_N  = (const float*)d_in[1];
  const float* b_N  = (const float*)d_in[2];
  const float* W_up = (const float*)d_in[3];
  const float* b_up = (const float*)d_in[4];
  const float* mu   = (const float*)d_in[5];
  const float* Wih0 = (const float*)d_in[6];
  const float* Whh0 = (const float*)d_in[7];
  const float* bih0 = (const float*)d_in[8];
  const float* bhh0 = (const float*)d_in[9];
  const float* Wih1 = (const float*)d_in[10];
  const float* Whh1 = (const float*)d_in[11];
  const float* bih1 = (const float*)d_in[12];
  const float* bhh1 = (const float*)d_in[13];
  const float* Wv   = (const float*)d_in[14];
  const float* bvv  = (const float*)d_in[15];
  float* wsF = (float*)d_ws;
  float* xwp = wsF + WS_XW;
  float* outF = (float*)d_out;

  prep_cols_kernel<<<513, 256, 0, stream>>>(W_N, b_N, W_up, b_up, wsF);
  prep_mu_kernel<<<1, 128, 0, stream>>>(mu, Wih0, bih0, bhh0, wsF);
  xw_kernel<<<B_, 512, 0, stream>>>(x, Wih0, wsF, xwp);
  lstm_kernel<<<B_, 384, 0, stream>>>(xwp, wsF, Whh0, Wih1, Whh1,
                                      bih1, bhh1, Wv, bvv, outF);
}

// Round 8
// 137.627 us; speedup vs baseline: 3.6967x; 1.0577x over previous
//
#include <hip/hip_runtime.h>
#include <hip/hip_bf16.h>

#define B_ 256
#define S_ 512
#define F_ 256
#define L_ 20

// ws layout (floats):
//   [0,10240)      W_combT [512][20]
//   [10240,10260)  b_comb[20]
//   [10260,10340)  xw_mu[80]  = bih0+bhh0 + W_ih0·mu
//   [10340,10420)  bsum[80]   = bih0+bhh0
//   [16384, +256*256*80) xw0[b][f][80] = bsum + W_ih0·x_up[b][f][:]
#define WS_WCT 0
#define WS_BC  10240
#define WS_XWMU 10260
#define WS_BSUM 10340
#define WS_XW  16384

#define LOAD20(dst, ptr) { const float4* _p = (const float4*)(ptr); \
  float4 _a=_p[0], _b=_p[1], _c=_p[2], _d=_p[3], _e=_p[4]; \
  dst[0]=_a.x; dst[1]=_a.y; dst[2]=_a.z; dst[3]=_a.w; \
  dst[4]=_b.x; dst[5]=_b.y; dst[6]=_b.z; dst[7]=_b.w; \
  dst[8]=_c.x; dst[9]=_c.y; dst[10]=_c.z; dst[11]=_c.w; \
  dst[12]=_d.x; dst[13]=_d.y; dst[14]=_d.z; dst[15]=_d.w; \
  dst[16]=_e.x; dst[17]=_e.y; dst[18]=_e.z; dst[19]=_e.w; }

// Non-rematerializable weight load: compiler cannot re-execute volatile asm,
// so the loaded value MUST stay register-resident across the loop.
#define GISSUE4(dst, ptr) asm volatile("global_load_dwordx4 %0, %1, off" \
  : "=v"(dst) : "v"(ptr) : "memory")
#define GWAIT() { asm volatile("s_waitcnt vmcnt(0)" ::: "memory"); \
  __builtin_amdgcn_sched_barrier(0); }
#define MEMFENCE() asm volatile("" ::: "memory")
#define LGKM0() asm volatile("s_waitcnt lgkmcnt(0)" ::: "memory")

// dot of a 5xfloat4 register row with a 20-float array, 4-acc ILP
#define DOT20(res, W, S, init0, init1) { \
  float _a0 = (init0), _a1 = (init1), _a2 = 0.f, _a3 = 0.f; \
  _a0 = fmaf(W[0].x, S[0], _a0);  _a1 = fmaf(W[0].y, S[1], _a1); \
  _a2 = fmaf(W[0].z, S[2], _a2);  _a3 = fmaf(W[0].w, S[3], _a3); \
  _a0 = fmaf(W[1].x, S[4], _a0);  _a1 = fmaf(W[1].y, S[5], _a1); \
  _a2 = fmaf(W[1].z, S[6], _a2);  _a3 = fmaf(W[1].w, S[7], _a3); \
  _a0 = fmaf(W[2].x, S[8], _a0);  _a1 = fmaf(W[2].y, S[9], _a1); \
  _a2 = fmaf(W[2].z, S[10], _a2); _a3 = fmaf(W[2].w, S[11], _a3); \
  _a0 = fmaf(W[3].x, S[12], _a0); _a1 = fmaf(W[3].y, S[13], _a1); \
  _a2 = fmaf(W[3].z, S[14], _a2); _a3 = fmaf(W[3].w, S[15], _a3); \
  _a0 = fmaf(W[4].x, S[16], _a0); _a1 = fmaf(W[4].y, S[17], _a1); \
  _a2 = fmaf(W[4].z, S[18], _a2); _a3 = fmaf(W[4].w, S[19], _a3); \
  res = (_a0 + _a1) + (_a2 + _a3); }

#define GLOAD_ROW5(W, base) { \
  GISSUE4(W[0], (base) + 0);  GISSUE4(W[1], (base) + 4); \
  GISSUE4(W[2], (base) + 8);  GISSUE4(W[3], (base) + 12); \
  GISSUE4(W[4], (base) + 16); }

// ---------------- kernel 1a: W_combT columns + b_comb ----------------
__global__ __launch_bounds__(256) void prep_cols_kernel(
    const float* __restrict__ W_N, const float* __restrict__ b_N,
    const float* __restrict__ W_up, const float* __restrict__ b_up,
    float* __restrict__ wsF)
{
  __shared__ float wn[512];
  int s = blockIdx.x;                 // 0..511 -> column s; 512 -> b_comb
  int tid = threadIdx.x;
  bool isb = (s == 512);
  if (isb) {
    wn[tid] = b_N[tid];
    wn[tid + 256] = b_N[tid + 256];
  } else {
    wn[tid] = W_N[(size_t)tid * S_ + s];
    wn[tid + 256] = W_N[(size_t)(tid + 256) * S_ + s];
  }
  __syncthreads();
  int w = tid >> 6, lane = tid & 63;
#pragma unroll
  for (int li = 0; li < 5; ++li) {
    int l = w * 5 + li;
    const float* wu = W_up + (size_t)l * S_;
    float acc = 0.f;
#pragma unroll
    for (int j = 0; j < 8; ++j)
      acc = fmaf(wu[lane + 64 * j], wn[lane + 64 * j], acc);
    acc += __shfl_xor(acc, 1);  acc += __shfl_xor(acc, 2);
    acc += __shfl_xor(acc, 4);  acc += __shfl_xor(acc, 8);
    acc += __shfl_xor(acc, 16); acc += __shfl_xor(acc, 32);
    if (lane == 0) {
      if (isb) wsF[WS_BC + l] = acc + b_up[l];
      else     wsF[WS_WCT + s * 20 + l] = acc;
    }
  }
}

// ---------------- kernel 1b: xw_mu + bsum ----------------
__global__ __launch_bounds__(128) void prep_mu_kernel(
    const float* __restrict__ mu, const float* __restrict__ Wih0,
    const float* __restrict__ bih0, const float* __restrict__ bhh0,
    float* __restrict__ wsF)
{
  int tid = threadIdx.x;
  if (tid < 80) {
    float bs = bih0[tid] + bhh0[tid];
    wsF[WS_BSUM + tid] = bs;
    float acc = bs;
#pragma unroll
    for (int l = 0; l < 20; ++l) acc = fmaf(Wih0[tid * 20 + l], mu[l], acc);
    wsF[WS_XWMU + tid] = acc;
  }
}

// ---------------- kernel 2: x -> x_up -> xw0 (L1 gate pre-projections) ----------------
__global__ __launch_bounds__(512) void xw_kernel(
    const float* __restrict__ x, const float* __restrict__ Wih0,
    const float* __restrict__ wsF, float* __restrict__ xw)
{
  __shared__ __align__(16) float Wl[10240];      // W_combT, 40KB
  __shared__ __align__(16) float xu[F_ * L_];    // x_up tile, 20KB
  __shared__ __align__(16) float Wg[80 * 20];    // W_ih0, 6.4KB
  __shared__ float bsumL[80];
  __shared__ float bcL[20];
  int b = blockIdx.x;
  int tid = threadIdx.x;
  {
    const float4* srcw = (const float4*)(wsF + WS_WCT);
    float4* dstw = (float4*)Wl;
    for (int i = tid; i < 2560; i += 512) dstw[i] = srcw[i];
    const float4* srcg = (const float4*)Wih0;
    float4* dstg = (float4*)Wg;
    for (int i = tid; i < 400; i += 512) dstg[i] = srcg[i];
    if (tid < 80) bsumL[tid] = wsF[WS_BSUM + tid];
    if (tid < 20) bcL[tid] = wsF[WS_BC + tid];
  }
  __syncthreads();
  int f = tid & 255;
  int p = tid >> 8;                 // s-parity split
  float acc[20];
#pragma unroll
  for (int l = 0; l < 20; ++l) acc[l] = 0.f;
  const float* xb = x + (size_t)b * S_ * F_ + f;
#pragma unroll 1
  for (int sg = 0; sg < S_; sg += 16) {
    float xv[8];
#pragma unroll
    for (int u = 0; u < 8; ++u) xv[u] = xb[(size_t)(sg + p + 2 * u) * F_];
#pragma unroll
    for (int u = 0; u < 8; ++u) {
      int s = sg + p + 2 * u;
      const float4* wp = (const float4*)(Wl + s * 20);
      float4 w0 = wp[0], w1 = wp[1], w2 = wp[2], w3 = wp[3], w4 = wp[4];
      acc[0] = fmaf(w0.x, xv[u], acc[0]);  acc[1] = fmaf(w0.y, xv[u], acc[1]);
      acc[2] = fmaf(w0.z, xv[u], acc[2]);  acc[3] = fmaf(w0.w, xv[u], acc[3]);
      acc[4] = fmaf(w1.x, xv[u], acc[4]);  acc[5] = fmaf(w1.y, xv[u], acc[5]);
      acc[6] = fmaf(w1.z, xv[u], acc[6]);  acc[7] = fmaf(w1.w, xv[u], acc[7]);
      acc[8] = fmaf(w2.x, xv[u], acc[8]);  acc[9] = fmaf(w2.y, xv[u], acc[9]);
      acc[10] = fmaf(w2.z, xv[u], acc[10]); acc[11] = fmaf(w2.w, xv[u], acc[11]);
      acc[12] = fmaf(w3.x, xv[u], acc[12]); acc[13] = fmaf(w3.y, xv[u], acc[13]);
      acc[14] = fmaf(w3.z, xv[u], acc[14]); acc[15] = fmaf(w3.w, xv[u], acc[15]);
      acc[16] = fmaf(w4.x, xv[u], acc[16]); acc[17] = fmaf(w4.y, xv[u], acc[17]);
      acc[18] = fmaf(w4.z, xv[u], acc[18]); acc[19] = fmaf(w4.w, xv[u], acc[19]);
    }
  }
  if (p == 1) {
#pragma unroll
    for (int l = 0; l < 20; ++l) xu[f * 20 + l] = acc[l];
  }
  __syncthreads();
  if (p == 0) {
#pragma unroll
    for (int l = 0; l < 20; ++l) xu[f * 20 + l] = acc[l] + xu[f * 20 + l] + bcL[l];
  }
  __syncthreads();
  // projection: thread (f2, half) computes gates [half*40, half*40+40)
  int f2 = tid >> 1, half = tid & 1;
  float xr[20];
  LOAD20(xr, xu + f2 * 20);
  float* ob = xw + ((size_t)b * 256 + f2) * 80 + half * 40;
  const float* wgbase = Wg + half * 40 * 20;
  const float* bsb = bsumL + half * 40;
#pragma unroll 2
  for (int g = 0; g < 40; ++g) {
    const float4* wp = (const float4*)(wgbase + g * 20);
    float4 w0 = wp[0], w1 = wp[1], w2 = wp[2], w3 = wp[3], w4 = wp[4];
    float a0 = bsb[g], a1 = 0.f, a2 = 0.f, a3 = 0.f;
    a0 = fmaf(w0.x, xr[0], a0);  a1 = fmaf(w0.y, xr[1], a1);
    a2 = fmaf(w0.z, xr[2], a2);  a3 = fmaf(w0.w, xr[3], a3);
    a0 = fmaf(w1.x, xr[4], a0);  a1 = fmaf(w1.y, xr[5], a1);
    a2 = fmaf(w1.z, xr[6], a2);  a3 = fmaf(w1.w, xr[7], a3);
    a0 = fmaf(w2.x, xr[8], a0);  a1 = fmaf(w2.y, xr[9], a1);
    a2 = fmaf(w2.z, xr[10], a2); a3 = fmaf(w2.w, xr[11], a3);
    a0 = fmaf(w3.x, xr[12], a0); a1 = fmaf(w3.y, xr[13], a1);
    a2 = fmaf(w3.z, xr[14], a2); a3 = fmaf(w3.w, xr[15], a3);
    a0 = fmaf(w4.x, xr[16], a0); a1 = fmaf(w4.y, xr[17], a1);
    a2 = fmaf(w4.z, xr[18], a2); a3 = fmaf(w4.w, xr[19], a3);
    ob[g] = (a0 + a1) + (a2 + a3);
  }
}

// ---------------- kernel 3: lock-free producer/consumer LSTM ----------
// Block = 256 threads = 4 waves = 2 chains x 2 roles, 1 wave per SIMD.
//   producer: L1 recurrence + xp2 = b1 + Wih1*h1, written to a 32-deep LDS ring.
//   consumer: L2 recurrence reading xp2 from the ring.
// NO per-step barriers. Sync = volatile LDS progress counters:
//   pcnt[chain]: producer steps completed; ccnt[chain]: consumer steps completed.
//   Producer updates pcnt once per 4 steps (after lgkmcnt(0) drains data writes);
//   consumer polls pcnt once per 4 steps and prefetches 4 slots; backpressure
//   via ccnt checked every 16 producer steps (ring never overwritten unread).
__device__ __forceinline__ float rlf(float v, int k) {
  return __int_as_float(__builtin_amdgcn_readlane(__float_as_int(v), k));
}
__device__ __forceinline__ float sigm(float x) {
  return __builtin_amdgcn_rcpf(1.f + __expf(-x));
}
__device__ __forceinline__ float tanh_fast(float x) {
  return fmaf(2.f, __builtin_amdgcn_rcpf(1.f + __expf(-2.f * x)), -1.f);
}

#define READ_H(dst, src) { \
  dst[0]=rlf(src,0);  dst[1]=rlf(src,1);  dst[2]=rlf(src,2);  dst[3]=rlf(src,3); \
  dst[4]=rlf(src,4);  dst[5]=rlf(src,5);  dst[6]=rlf(src,6);  dst[7]=rlf(src,7); \
  dst[8]=rlf(src,8);  dst[9]=rlf(src,9);  dst[10]=rlf(src,10); dst[11]=rlf(src,11); \
  dst[12]=rlf(src,12); dst[13]=rlf(src,13); dst[14]=rlf(src,14); dst[15]=rlf(src,15); \
  dst[16]=rlf(src,16); dst[17]=rlf(src,17); dst[18]=rlf(src,18); dst[19]=rlf(src,19); }

// producer step STEP (1..256): L1 from prefetched xw slot, then xp2 into ring
#define PSTEP(PA, PB, STEP) { \
  float preA, preB; \
  DOT20(preA, wA, sh1, PA, 0.f); \
  DOT20(preB, wB, sh1, PB, 0.f); \
  PA = prow[rA]; PB = prow[rB]; \
  prow += ((STEP) <= 251) ? pstep : 0; \
  float aA = fmaf(actA, __builtin_amdgcn_rcpf(1.f + __expf(actB * preA)), actC); \
  float aB = sigm(preB); \
  float fv = __shfl(aA, lf); \
  float gv = __shfl(aA, lg); \
  c1 = fmaf(fv, c1, aA * gv); \
  float h1j = aB * tanh_fast(c1); \
  READ_H(sh1, h1j); \
  float xpA, xpB; \
  DOT20(xpA, iA, sh1, bA1c, 0.f); \
  DOT20(xpB, iB, sh1, bB1c, 0.f); \
  xpring[chain][(STEP) & 31][lane] = xpA; \
  xpring[chain][(STEP) & 31][64 + lane] = xpB; }

// consumer step: L2 from ring-prefetched xp
#define CSTEP(XA, XB) { \
  float preA, preB; \
  DOT20(preA, hA, sh2, XA, 0.f); \
  DOT20(preB, hB, sh2, XB, 0.f); \
  float aA = fmaf(actA, __builtin_amdgcn_rcpf(1.f + __expf(actB * preA)), actC); \
  float aB = sigm(preB); \
  float fv = __shfl(aA, lf); \
  float gv = __shfl(aA, lg); \
  c2 = fmaf(fv, c2, aA * gv); \
  h2j = aB * tanh_fast(c2); \
  READ_H(sh2, h2j); }

__global__ __launch_bounds__(256, 1) void lstm_kernel(
    const float* __restrict__ xw, const float* __restrict__ wsF,
    const float* __restrict__ Whh0,
    const float* __restrict__ Wih1, const float* __restrict__ Whh1,
    const float* __restrict__ bih1, const float* __restrict__ bhh1,
    const float* __restrict__ Wv, const float* __restrict__ bv,
    float* __restrict__ out)
{
  __shared__ __align__(16) float xpring[2][32][128];  // 32 KB ring
  __shared__ int pcntS[2];
  __shared__ int ccntS[2];
  __shared__ float hb[2][20];
  int b = blockIdx.x;
  int tid = threadIdx.x;
  int wid = tid >> 6;
  int lane = tid & 63;
  int chain = wid >> 1;      // 0 = fwd chain b, 1 = rev chain B+b
  int role = wid & 1;        // 0 = producer (L1+xp2), 1 = consumer (L2)
  int jmod = lane % 20;
  int rA = lane, rB = 60 + jmod;
  int lf = (lane + 20) & 63;
  int lg = (lane + 40) & 63;
  int typ = lane / 20;
  float actB = (typ == 2) ? -2.f : -1.f;
  float actA = (typ == 2) ? 2.f : 1.f;
  float actC = (typ == 2) ? -1.f : 0.f;

  if (tid < 2) { pcntS[tid] = 0; ccntS[tid] = 0; }
  __syncthreads();
  volatile int* pcnt = &pcntS[chain];
  volatile int* ccnt = &ccntS[chain];

  if (role == 0) {
    // ---------------- producer ----------------
    float4 wA[5], wB[5], iA[5], iB[5];
    GLOAD_ROW5(wA, Whh0 + rA * 20);
    GLOAD_ROW5(wB, Whh0 + rB * 20);
    GLOAD_ROW5(iA, Wih1 + rA * 20);
    GLOAD_ROW5(iB, Wih1 + rB * 20);
    GWAIT();
    float bA1c = bih1[rA] + bhh1[rA];
    float bB1c = bih1[rB] + bhh1[rB];
    const float* prow = xw + ((size_t)b * 256 + (chain ? 255 : 0)) * 80;
    int pstep = chain ? -80 : 80;
    float pA0 = prow[rA], pB0 = prow[rB]; prow += pstep;
    float pA1 = prow[rA], pB1 = prow[rB]; prow += pstep;
    float pA2 = prow[rA], pB2 = prow[rB]; prow += pstep;
    float pA3 = prow[rA], pB3 = prow[rB]; prow += pstep;   // -> row for step 5

    float sh1[20];
    float c1;
    {   // step 0: input = mu projection, h=c=0
      float preA = wsF[WS_XWMU + rA];
      float preB = wsF[WS_XWMU + rB];
      float aA = fmaf(actA, __builtin_amdgcn_rcpf(1.f + __expf(actB * preA)), actC);
      float aB = sigm(preB);
      float gv = __shfl(aA, lg);
      c1 = aA * gv;
      float h1j = aB * tanh_fast(c1);
      READ_H(sh1, h1j);
      float xpA, xpB;
      DOT20(xpA, iA, sh1, bA1c, 0.f);
      DOT20(xpB, iB, sh1, bB1c, 0.f);
      xpring[chain][0][lane] = xpA;
      xpring[chain][0][64 + lane] = xpB;
      LGKM0();
      *pcnt = 1;
      MEMFENCE();
    }
#pragma unroll 1
    for (int t = 1; t <= 253; t += 4) {
      if (((t - 1) & 15) == 0) {
        // backpressure: steps t..t+18 write slots needing consumer >= t+18-31
        while (*ccnt < t - 13) { }
        MEMFENCE();
      }
      PSTEP(pA0, pB0, t);
      PSTEP(pA1, pB1, t + 1);
      PSTEP(pA2, pB2, t + 2);
      PSTEP(pA3, pB3, t + 3);
      LGKM0();
      *pcnt = t + 4;
      MEMFENCE();
    }
  } else {
    // ---------------- consumer ----------------
    float4 hA[5], hB[5];
    GLOAD_ROW5(hA, Whh1 + rA * 20);
    GLOAD_ROW5(hB, Whh1 + rB * 20);
    GWAIT();
    float sh2[20];
#pragma unroll
    for (int k = 0; k < 20; ++k) sh2[k] = 0.f;
    float c2 = 0.f;
    float h2j = 0.f;
#pragma unroll 1
    for (int t = 0; t <= 252; t += 4) {
      while (*pcnt < t + 4) { }
      MEMFENCE();
      int sl = t & 31;                    // t%4==0 -> slots sl..sl+3 contiguous
      float xA0 = xpring[chain][sl][lane],     xB0 = xpring[chain][sl][64 + lane];
      float xA1 = xpring[chain][sl + 1][lane], xB1 = xpring[chain][sl + 1][64 + lane];
      float xA2 = xpring[chain][sl + 2][lane], xB2 = xpring[chain][sl + 2][64 + lane];
      float xA3 = xpring[chain][sl + 3][lane], xB3 = xpring[chain][sl + 3][64 + lane];
      CSTEP(xA0, xB0);
      CSTEP(xA1, xB1);
      CSTEP(xA2, xB2);
      CSTEP(xA3, xB3);
      *ccnt = t + 4;
      MEMFENCE();
    }
    {   // tail step t=256
      while (*pcnt < 257) { }
      MEMFENCE();
      float xA = xpring[chain][256 & 31][lane];
      float xB = xpring[chain][256 & 31][64 + lane];
      CSTEP(xA, xB);
      if (lane < 20) hb[chain][lane] = h2j;
    }
  }

  __syncthreads();
  if (tid == 0) {
    float y = bv[0];
#pragma unroll
    for (int j = 0; j < 20; ++j) y = fmaf(Wv[j], hb[0][j], y);
#pragma unroll
    for (int j = 0; j < 20; ++j) y = fmaf(Wv[20 + j], hb[1][j], y);
    out[b] = y;
  }
}

extern "C" void kernel_launch(void* const* d_in, const int* in_sizes, int n_in,
                              void* d_out, int out_size, void* d_ws, size_t ws_size,
                              hipStream_t stream)
{
  const float* x    = (const float*)d_in[0];
  const float* W_N  = (const float*)d_in[1];
  const float* b_N  = (const float*)d_in[2];
  const float* W_up = (const float*)d_in[3];
  const float* b_up = (const float*)d_in[4];
  const float* mu   = (const float*)d_in[5];
  const float* Wih0 = (const float*)d_in[6];
  const float* Whh0 = (const float*)d_in[7];
  const float* bih0 = (const float*)d_in[8];
  const float* bhh0 = (const float*)d_in[9];
  const float* Wih1 = (const float*)d_in[10];
  const float* Whh1 = (const float*)d_in[11];
  const float* bih1 = (const float*)d_in[12];
  const float* bhh1 = (const float*)d_in[13];
  const float* Wv   = (const float*)d_in[14];
  const float* bvv  = (const float*)d_in[15];
  float* wsF = (float*)d_ws;
  float* xwp = wsF + WS_XW;
  float* outF = (float*)d_out;

  prep_cols_kernel<<<513, 256, 0, stream>>>(W_N, b_N, W_up, b_up, wsF);
  prep_mu_kernel<<<1, 128, 0, stream>>>(mu, Wih0, bih0, bhh0, wsF);
  xw_kernel<<<B_, 512, 0, stream>>>(x, Wih0, wsF, xwp);
  lstm_kernel<<<B_, 256, 0, stream>>>(xwp, wsF, Whh0, Wih1, Whh1,
                                      bih1, bhh1, Wv, bvv, outF);
}